// Round 1
// baseline (4493.847 us; speedup 1.0000x reference)
//
#include <hip/hip_runtime.h>
#include <hip/hip_bf16.h>

#define N_NODES 50000
#define N_EDGES 640000
#define HID 128

typedef float f32x4 __attribute__((ext_vector_type(4)));
typedef short s16x8 __attribute__((ext_vector_type(8)));
typedef __hip_bfloat16 bf16;

// ---- fragment load helpers -------------------------------------------------
// LDS A-fragment: 8 bf16 at 8B-aligned address (row strides are multiples of 8B)
__device__ __forceinline__ s16x8 ld_frag_lds(const bf16* p) {
  union { uint2 u[2]; s16x8 v; } r;
  r.u[0] = *(const uint2*)(p);
  r.u[1] = *(const uint2*)(p + 4);
  return r.v;
}
// global B-fragment: 16B aligned, pre-swizzled [kc][n][32]
__device__ __forceinline__ s16x8 ld_frag_g(const bf16* p) {
  union { uint4 u; s16x8 v; } r;
  r.u = *(const uint4*)(p);
  return r.v;
}
__device__ __forceinline__ float sigm(float v) { return 1.f / (1.f + __expf(-v)); }

// ---- prep kernels ----------------------------------------------------------
__global__ void cvt_h_kernel(const float* __restrict__ src, bf16* __restrict__ dst, int n) {
  int i = blockIdx.x * 256 + threadIdx.x;
  if (i < n) dst[i] = __float2bfloat16(src[i]);
}

__global__ void copy_x_kernel(const float* __restrict__ src, float* __restrict__ dst, int n) {
  int i = blockIdx.x * 256 + threadIdx.x;
  if (i < n) dst[i] = src[i];
}

// pack weight [K x 128] fp32 row-major -> bf16 B-fragment order [kc][n][kk],
// kk = q*8+j so a lane's 8 k-values are 16B contiguous; zero-pad k >= K.
__global__ void pack_w_kernel(const float* __restrict__ src, bf16* __restrict__ dst,
                              int K, int Kpad) {
  int i = blockIdx.x * 256 + threadIdx.x;
  if (i >= Kpad * HID) return;
  int kk = i & 31;
  int n  = (i >> 5) & 127;
  int kc = i >> 12;
  int k  = kc * 32 + kk;
  float v = (k < K) ? src[(size_t)k * HID + n] : 0.f;
  dst[i] = __float2bfloat16(v);
}

// ---- fused edge kernel -----------------------------------------------------
// block = 256 threads (4 waves, 2x2 wave grid), 128 edges/block, BN=128.
// mfma_f32_16x16x32_bf16 layouts (m89/m91-verified):
//   A: lane holds A[m=lane&15][k=(lane>>4)*8+j]
//   B: lane holds B[k=(lane>>4)*8+j][n=lane&15]
//   C/D: lane reg r holds C[row=(lane>>4)*4+r][col=lane&15]
__global__ __launch_bounds__(256, 2)
void edge_kernel(const bf16* __restrict__ hb, const float* __restrict__ x,
                 const int* __restrict__ srci, const int* __restrict__ dsti,
                 const float* __restrict__ eattr,
                 const bf16* __restrict__ w1p, const bf16* __restrict__ w2p,
                 const bf16* __restrict__ xw1p,
                 const float* __restrict__ em_b1, const float* __restrict__ em_b2,
                 const float* __restrict__ ei_w, const float* __restrict__ ei_b,
                 const float* __restrict__ xm_b1, const float* __restrict__ xm_w2,
                 float* __restrict__ mi, float* __restrict__ xout) {
  __shared__ bf16 Abuf[128 * 36];    // [128 edges x 32 k], stride 36 (bank spread)
  __shared__ bf16 Tbuf[128 * 132];   // t1 / mij round-trip, stride 132
  __shared__ float rxL[128], ryL[128], rzL[128], invdL[128], eijL[128];
  __shared__ float xpart[2][128];
  __shared__ float b1L[HID], b2L[HID], xb1L[HID], eiwL[HID], w2xL[HID];
  __shared__ float eibL;

  const int tid = threadIdx.x;
  const int e0  = blockIdx.x * 128;
  if (tid < HID) {
    b1L[tid]  = em_b1[tid];  b2L[tid]  = em_b2[tid];
    xb1L[tid] = xm_b1[tid];  eiwL[tid] = ei_w[tid];  w2xL[tid] = xm_w2[tid];
  }
  if (tid == 0) eibL = ei_b[0];

  const int lane = tid & 63, wv = tid >> 6;
  const int wrow = wv >> 1, wcol = wv & 1;
  const int q = lane >> 4, ml = lane & 15;
  const int mbase = wrow * 64, nbase = wcol * 64;

  const int se = tid >> 1, sh = tid & 1;        // staging: 2 threads per edge row
  const int sdst = dsti[e0 + se], ssrc = srci[e0 + se];

  const f32x4 zf = {0.f, 0.f, 0.f, 0.f};
  f32x4 acc[4][4];
#pragma unroll
  for (int a = 0; a < 4; ++a)
#pragma unroll
    for (int b = 0; b < 4; ++b) acc[a][b] = zf;

  // ---------------- stage 1: t1 = silu(edge_in @ em_w1 + b1), K = 288 ------
  for (int c = 0; c < 9; ++c) {
    if (c < 8) {   // hi (c<4) | hj chunks from bf16 h
      const int node = (c < 4) ? sdst : ssrc;
      const bf16* p = hb + (size_t)node * HID + (c & 3) * 32 + sh * 16;
      uint4 v0 = *(const uint4*)p;
      uint4 v1 = *(const uint4*)(p + 8);
      bf16* d = Abuf + se * 36 + sh * 16;
      ((uint2*)d)[0] = make_uint2(v0.x, v0.y);
      ((uint2*)d)[1] = make_uint2(v0.z, v0.w);
      ((uint2*)d)[2] = make_uint2(v1.x, v1.y);
      ((uint2*)d)[3] = make_uint2(v1.z, v1.w);
    } else {       // [d_sq | edge_attr(16) | zeros(15)]
      bf16* d = Abuf + se * 36;
      const float* ap = eattr + (size_t)(e0 + se) * 16;
      if (sh == 0) {
        const float* xd = x + 3 * sdst;
        const float* xs = x + 3 * ssrc;
        float dx = xd[0] - xs[0], dy = xd[1] - xs[1], dz = xd[2] - xs[2];
        float dsq = dx * dx + dy * dy + dz * dz;
        rxL[se] = dx; ryL[se] = dy; rzL[se] = dz;
        invdL[se] = 1.f / (sqrtf(dsq + 1e-8f) + 1.f);
        d[0] = __float2bfloat16(dsq);
#pragma unroll
        for (int j = 0; j < 15; ++j) d[1 + j] = __float2bfloat16(ap[j]);
      } else {
        d[16] = __float2bfloat16(ap[15]);
        bf16 z = __float2bfloat16(0.f);
#pragma unroll
        for (int j = 17; j < 32; ++j) d[j] = z;
      }
    }
    __syncthreads();
    s16x8 af[4];
#pragma unroll
    for (int mt = 0; mt < 4; ++mt)
      af[mt] = ld_frag_lds(Abuf + (mbase + mt * 16 + ml) * 36 + q * 8);
#pragma unroll
    for (int nt = 0; nt < 4; ++nt) {
      const int n = nbase + nt * 16 + ml;
      s16x8 bfr = ld_frag_g(w1p + (size_t)(c * HID + n) * 32 + q * 8);
#pragma unroll
      for (int mt = 0; mt < 4; ++mt)
        acc[mt][nt] = __builtin_amdgcn_mfma_f32_16x16x32_bf16(af[mt], bfr, acc[mt][nt], 0, 0, 0);
    }
    __syncthreads();
  }

  // epilogue 1: silu -> Tbuf (C-layout -> LDS row-major = A-layout for stage 2)
#pragma unroll
  for (int mt = 0; mt < 4; ++mt)
#pragma unroll
    for (int nt = 0; nt < 4; ++nt)
#pragma unroll
      for (int r = 0; r < 4; ++r) {
        int row = mbase + mt * 16 + q * 4 + r;
        int col = nbase + nt * 16 + ml;
        float v = acc[mt][nt][r] + b1L[col];
        v *= sigm(v);
        Tbuf[row * 132 + col] = __float2bfloat16(v);
      }
  __syncthreads();

  // ---------------- stage 2: mij = t1 @ em_w2 + b2, K = 128 ----------------
#pragma unroll
  for (int a = 0; a < 4; ++a)
#pragma unroll
    for (int b = 0; b < 4; ++b) acc[a][b] = zf;
  for (int kc = 0; kc < 4; ++kc) {
    s16x8 af[4];
#pragma unroll
    for (int mt = 0; mt < 4; ++mt)
      af[mt] = ld_frag_lds(Tbuf + (mbase + mt * 16 + ml) * 132 + kc * 32 + q * 8);
#pragma unroll
    for (int nt = 0; nt < 4; ++nt) {
      const int n = nbase + nt * 16 + ml;
      s16x8 bfr = ld_frag_g(w2p + (size_t)(kc * HID + n) * 32 + q * 8);
#pragma unroll
      for (int mt = 0; mt < 4; ++mt)
        acc[mt][nt] = __builtin_amdgcn_mfma_f32_16x16x32_bf16(af[mt], bfr, acc[mt][nt], 0, 0, 0);
    }
  }
  __syncthreads();   // all waves done reading t1 from Tbuf

  // write mij (+b2) into Tbuf
#pragma unroll
  for (int mt = 0; mt < 4; ++mt)
#pragma unroll
    for (int nt = 0; nt < 4; ++nt)
#pragma unroll
      for (int r = 0; r < 4; ++r) {
        int row = mbase + mt * 16 + q * 4 + r;
        int col = nbase + nt * 16 + ml;
        Tbuf[row * 132 + col] = __float2bfloat16(acc[mt][nt][r] + b2L[col]);
      }
  __syncthreads();

  // eij = sigmoid(mij . ei_w + ei_b), 2 threads per edge
  {
    float s = 0.f;
    const bf16* mrow = Tbuf + se * 132 + sh * 64;
#pragma unroll
    for (int j = 0; j < 64; ++j) s += __bfloat162float(mrow[j]) * eiwL[sh * 64 + j];
    s += __shfl_xor(s, 1);
    if (sh == 0) eijL[se] = sigm(s + eibL);
  }
  __syncthreads();

  // mi scatter: mi[dst] += mij * eij   (fp32 HW atomics)
  {
    const float ev = eijL[se];
    float* mp = mi + (size_t)sdst * HID + sh * 64;
    const bf16* mrow = Tbuf + se * 132 + sh * 64;
#pragma unroll
    for (int j = 0; j < 64; ++j)
      unsafeAtomicAdd(mp + j, __bfloat162float(mrow[j]) * ev);
  }

  // ---------------- x branch: t2 = silu(mij @ xm_w1 + b), gate = tanh(t2 . xm_w2)
#pragma unroll
  for (int a = 0; a < 4; ++a)
#pragma unroll
    for (int b = 0; b < 4; ++b) acc[a][b] = zf;
  for (int kc = 0; kc < 4; ++kc) {
    s16x8 af[4];
#pragma unroll
    for (int mt = 0; mt < 4; ++mt)
      af[mt] = ld_frag_lds(Tbuf + (mbase + mt * 16 + ml) * 132 + kc * 32 + q * 8);
#pragma unroll
    for (int nt = 0; nt < 4; ++nt) {
      const int n = nbase + nt * 16 + ml;
      s16x8 bfr = ld_frag_g(xw1p + (size_t)(kc * HID + n) * 32 + q * 8);
#pragma unroll
      for (int mt = 0; mt < 4; ++mt)
        acc[mt][nt] = __builtin_amdgcn_mfma_f32_16x16x32_bf16(af[mt], bfr, acc[mt][nt], 0, 0, 0);
    }
  }
  float part[16];
#pragma unroll
  for (int i = 0; i < 16; ++i) part[i] = 0.f;
#pragma unroll
  for (int mt = 0; mt < 4; ++mt)
#pragma unroll
    for (int nt = 0; nt < 4; ++nt)
#pragma unroll
      for (int r = 0; r < 4; ++r) {
        int col = nbase + nt * 16 + ml;
        float v = acc[mt][nt][r] + xb1L[col];
        v *= sigm(v);
        part[mt * 4 + r] += v * w2xL[col];
      }
#pragma unroll
  for (int i = 0; i < 16; ++i) {   // reduce over 16 lanes sharing a row
    float v = part[i];
    v += __shfl_xor(v, 1); v += __shfl_xor(v, 2);
    v += __shfl_xor(v, 4); v += __shfl_xor(v, 8);
    if (ml == 0) xpart[wcol][mbase + (i >> 2) * 16 + q * 4 + (i & 3)] = v;
  }
  __syncthreads();
  if (tid < 128) {
    float g  = tanhf(xpart[0][tid] + xpart[1][tid]);
    float sc = invdL[tid] * g;
    int dn = dsti[e0 + tid];
    unsafeAtomicAdd(xout + dn * 3 + 0, rxL[tid] * sc);
    unsafeAtomicAdd(xout + dn * 3 + 1, ryL[tid] * sc);
    unsafeAtomicAdd(xout + dn * 3 + 2, rzL[tid] * sc);
  }
}

// ---- node kernel: h_out = h + MLP([mi|h]) ---------------------------------
__global__ __launch_bounds__(256, 2)
void node_kernel(const float* __restrict__ mi, const bf16* __restrict__ hb,
                 const float* __restrict__ h,
                 const bf16* __restrict__ nw1p, const bf16* __restrict__ nw2p,
                 const float* __restrict__ nb1, const float* __restrict__ nb2,
                 float* __restrict__ hout) {
  __shared__ bf16 Abuf[128 * 36];
  __shared__ bf16 Tbuf[128 * 132];
  __shared__ float b1L[HID], b2L[HID];
  const int tid = threadIdx.x;
  const int n0 = blockIdx.x * 128;
  if (tid < HID) { b1L[tid] = nb1[tid]; b2L[tid] = nb2[tid]; }
  const int lane = tid & 63, wv = tid >> 6;
  const int wrow = wv >> 1, wcol = wv & 1;
  const int q = lane >> 4, ml = lane & 15;
  const int mbase = wrow * 64, nbase = wcol * 64;
  const int se = tid >> 1, sh = tid & 1;
  int node = n0 + se;
  if (node >= N_NODES) node = 0;   // clamp; stores masked below

  const f32x4 zf = {0.f, 0.f, 0.f, 0.f};
  f32x4 acc[4][4];
#pragma unroll
  for (int a = 0; a < 4; ++a)
#pragma unroll
    for (int b = 0; b < 4; ++b) acc[a][b] = zf;

  for (int c = 0; c < 8; ++c) {    // K = 256: [mi | h]
    bf16* d = Abuf + se * 36 + sh * 16;
    if (c < 4) {
      const float* p = mi + (size_t)node * HID + c * 32 + sh * 16;
#pragma unroll
      for (int j = 0; j < 16; ++j) d[j] = __float2bfloat16(p[j]);
    } else {
      const bf16* p = hb + (size_t)node * HID + (c - 4) * 32 + sh * 16;
      uint4 v0 = *(const uint4*)p;
      uint4 v1 = *(const uint4*)(p + 8);
      ((uint2*)d)[0] = make_uint2(v0.x, v0.y);
      ((uint2*)d)[1] = make_uint2(v0.z, v0.w);
      ((uint2*)d)[2] = make_uint2(v1.x, v1.y);
      ((uint2*)d)[3] = make_uint2(v1.z, v1.w);
    }
    __syncthreads();
    s16x8 af[4];
#pragma unroll
    for (int mt = 0; mt < 4; ++mt)
      af[mt] = ld_frag_lds(Abuf + (mbase + mt * 16 + ml) * 36 + q * 8);
#pragma unroll
    for (int nt = 0; nt < 4; ++nt) {
      const int n = nbase + nt * 16 + ml;
      s16x8 bfr = ld_frag_g(nw1p + (size_t)(c * HID + n) * 32 + q * 8);
#pragma unroll
      for (int mt = 0; mt < 4; ++mt)
        acc[mt][nt] = __builtin_amdgcn_mfma_f32_16x16x32_bf16(af[mt], bfr, acc[mt][nt], 0, 0, 0);
    }
    __syncthreads();
  }
  // u = silu(. + b1) -> Tbuf
#pragma unroll
  for (int mt = 0; mt < 4; ++mt)
#pragma unroll
    for (int nt = 0; nt < 4; ++nt)
#pragma unroll
      for (int r = 0; r < 4; ++r) {
        int row = mbase + mt * 16 + q * 4 + r;
        int col = nbase + nt * 16 + ml;
        float v = acc[mt][nt][r] + b1L[col];
        v *= sigm(v);
        Tbuf[row * 132 + col] = __float2bfloat16(v);
      }
  __syncthreads();
#pragma unroll
  for (int a = 0; a < 4; ++a)
#pragma unroll
    for (int b = 0; b < 4; ++b) acc[a][b] = zf;
  for (int kc = 0; kc < 4; ++kc) {
    s16x8 af[4];
#pragma unroll
    for (int mt = 0; mt < 4; ++mt)
      af[mt] = ld_frag_lds(Tbuf + (mbase + mt * 16 + ml) * 132 + kc * 32 + q * 8);
#pragma unroll
    for (int nt = 0; nt < 4; ++nt) {
      const int n = nbase + nt * 16 + ml;
      s16x8 bfr = ld_frag_g(nw2p + (size_t)(kc * HID + n) * 32 + q * 8);
#pragma unroll
      for (int mt = 0; mt < 4; ++mt)
        acc[mt][nt] = __builtin_amdgcn_mfma_f32_16x16x32_bf16(af[mt], bfr, acc[mt][nt], 0, 0, 0);
    }
  }
  // h_out = h + (. + b2), masked tail
#pragma unroll
  for (int mt = 0; mt < 4; ++mt)
#pragma unroll
    for (int nt = 0; nt < 4; ++nt)
#pragma unroll
      for (int r = 0; r < 4; ++r) {
        int row = mbase + mt * 16 + q * 4 + r;
        int nn = n0 + row;
        if (nn < N_NODES) {
          int col = nbase + nt * 16 + ml;
          size_t idx = (size_t)nn * HID + col;
          hout[idx] = h[idx] + acc[mt][nt][r] + b2L[col];
        }
      }
}

// ---- launcher --------------------------------------------------------------
extern "C" void kernel_launch(void* const* d_in, const int* in_sizes, int n_in,
                              void* d_out, int out_size, void* d_ws, size_t ws_size,
                              hipStream_t stream) {
  (void)in_sizes; (void)n_in; (void)out_size; (void)ws_size;
  const float* h     = (const float*)d_in[0];
  const float* x     = (const float*)d_in[1];
  const int*   eidx  = (const int*)  d_in[2];
  const float* eattr = (const float*)d_in[3];
  const float* em_w1 = (const float*)d_in[4];
  const float* em_b1 = (const float*)d_in[5];
  const float* em_w2 = (const float*)d_in[6];
  const float* em_b2 = (const float*)d_in[7];
  const float* ei_w  = (const float*)d_in[8];
  const float* ei_b  = (const float*)d_in[9];
  const float* xm_w1 = (const float*)d_in[10];
  const float* xm_b1 = (const float*)d_in[11];
  const float* xm_w2 = (const float*)d_in[12];
  const float* nm_w1 = (const float*)d_in[13];
  const float* nm_b1 = (const float*)d_in[14];
  const float* nm_w2 = (const float*)d_in[15];
  const float* nm_b2 = (const float*)d_in[16];

  float* hout = (float*)d_out;
  float* xout = hout + (size_t)N_NODES * HID;

  char* w = (char*)d_ws;
  float* mi  = (float*)w;  w += (size_t)N_NODES * HID * 4;
  bf16* hb   = (bf16*)w;   w += (size_t)N_NODES * HID * 2;
  bf16* w1p  = (bf16*)w;   w += 9 * HID * 32 * 2;
  bf16* w2p  = (bf16*)w;   w += 4 * HID * 32 * 2;
  bf16* xw1p = (bf16*)w;   w += 4 * HID * 32 * 2;
  bf16* nw1p = (bf16*)w;   w += 8 * HID * 32 * 2;
  bf16* nw2p = (bf16*)w;   w += 4 * HID * 32 * 2;

  hipMemsetAsync(mi, 0, (size_t)N_NODES * HID * 4, stream);
  cvt_h_kernel<<<(N_NODES * HID + 255) / 256, 256, 0, stream>>>(h, hb, N_NODES * HID);
  pack_w_kernel<<<(288 * HID + 255) / 256, 256, 0, stream>>>(em_w1, w1p, 273, 288);
  pack_w_kernel<<<(128 * HID + 255) / 256, 256, 0, stream>>>(em_w2, w2p, 128, 128);
  pack_w_kernel<<<(128 * HID + 255) / 256, 256, 0, stream>>>(xm_w1, xw1p, 128, 128);
  pack_w_kernel<<<(256 * HID + 255) / 256, 256, 0, stream>>>(nm_w1, nw1p, 256, 256);
  pack_w_kernel<<<(128 * HID + 255) / 256, 256, 0, stream>>>(nm_w2, nw2p, 128, 128);
  copy_x_kernel<<<(N_NODES * 3 + 255) / 256, 256, 0, stream>>>(x, xout, N_NODES * 3);

  edge_kernel<<<N_EDGES / 128, 256, 0, stream>>>(
      hb, x, eidx, eidx + N_EDGES, eattr, w1p, w2p, xw1p,
      em_b1, em_b2, ei_w, ei_b, xm_b1, xm_w2, mi, xout);
  node_kernel<<<(N_NODES + 127) / 128, 256, 0, stream>>>(
      mi, hb, h, nw1p, nw2p, nm_b1, nm_b2, hout);
}

// Round 2
// 790.980 us; speedup vs baseline: 5.6814x; 5.6814x over previous
//
#include <hip/hip_runtime.h>
#include <hip/hip_bf16.h>

#define N_NODES 50000
#define N_EDGES 640000
#define HID 128

typedef float f32x4 __attribute__((ext_vector_type(4)));
typedef short s16x8 __attribute__((ext_vector_type(8)));
typedef __hip_bfloat16 bf16;

// ---- helpers ---------------------------------------------------------------
__device__ __forceinline__ s16x8 ld_frag_lds(const bf16* p) {
  union { uint2 u[2]; s16x8 v; } r;
  r.u[0] = *(const uint2*)(p);
  r.u[1] = *(const uint2*)(p + 4);
  return r.v;
}
__device__ __forceinline__ s16x8 ld_frag_g(const bf16* p) {
  union { uint4 u; s16x8 v; } r;
  r.u = *(const uint4*)(p);
  return r.v;
}
__device__ __forceinline__ float sigm(float v) { return 1.f / (1.f + __expf(-v)); }
__device__ __forceinline__ float b2f(unsigned short u) {
  return __uint_as_float(((unsigned)u) << 16);
}

// ---- prep kernels ----------------------------------------------------------
__global__ void cvt_kernel(const float* __restrict__ src, bf16* __restrict__ dst, int n) {
  int i = blockIdx.x * 256 + threadIdx.x;
  if (i < n) dst[i] = __float2bfloat16(src[i]);
}
__global__ void copy_x_kernel(const float* __restrict__ src, float* __restrict__ dst, int n) {
  int i = blockIdx.x * 256 + threadIdx.x;
  if (i < n) dst[i] = src[i];
}
// weight [K x 128] fp32 row-major -> bf16 B-fragment order [kc][n][q*8+j]
__global__ void pack_w_kernel(const float* __restrict__ src, bf16* __restrict__ dst,
                              int K, int Kpad) {
  int i = blockIdx.x * 256 + threadIdx.x;
  if (i >= Kpad * HID) return;
  int kk = i & 31;
  int n  = (i >> 5) & 127;
  int kc = i >> 12;
  int k  = kc * 32 + kk;
  float v = (k < K) ? src[(size_t)k * HID + n] : 0.f;
  dst[i] = __float2bfloat16(v);
}

// ---- counting sort (CSR build) ---------------------------------------------
__global__ void hist_kernel(const int* __restrict__ dst, int* __restrict__ cnt) {
  int e = blockIdx.x * 256 + threadIdx.x;
  if (e < N_EDGES) atomicAdd(&cnt[dst[e]], 1);
}
__global__ void scan_kernel(const int* __restrict__ cnt, int* __restrict__ ptr,
                            int* __restrict__ work) {
  __shared__ int sums[1024];
  const int tid = threadIdx.x;
  const int CH = (N_NODES + 1023) / 1024;   // 49
  const int base = tid * CH;
  int s = 0;
  for (int i = 0; i < CH; ++i) { int idx = base + i; if (idx < N_NODES) s += cnt[idx]; }
  sums[tid] = s;
  __syncthreads();
  for (int off = 1; off < 1024; off <<= 1) {
    int v = (tid >= off) ? sums[tid - off] : 0;
    __syncthreads();
    sums[tid] += v;
    __syncthreads();
  }
  int run = (tid == 0) ? 0 : sums[tid - 1];
  for (int i = 0; i < CH; ++i) {
    int idx = base + i;
    if (idx < N_NODES) { ptr[idx] = run; work[idx] = run; run += cnt[idx]; }
  }
  if (tid == 1023) ptr[N_NODES] = sums[1023];
}
__global__ void scatter_kernel(const int* __restrict__ dst, int* __restrict__ work,
                               int* __restrict__ perm) {
  int e = blockIdx.x * 256 + threadIdx.x;
  if (e < N_EDGES) { int p = atomicAdd(&work[dst[e]], 1); perm[p] = e; }
}

// ---- fused edge kernel -----------------------------------------------------
// block = 256 threads (2x2 wave grid), 128 edges/block.
// MODE 0: legacy atomic scatter (fallback if ws too small). MODE 1: row writes.
template<int MODE>
__global__ __launch_bounds__(256, 4)
void edge_kernel(const bf16* __restrict__ hb, const float* __restrict__ x,
                 const int* __restrict__ srci, const int* __restrict__ dsti,
                 const float* __restrict__ eattr,
                 const bf16* __restrict__ w1p, const bf16* __restrict__ w2p,
                 const bf16* __restrict__ xw1p,
                 const float* __restrict__ em_b1, const float* __restrict__ em_b2,
                 const float* __restrict__ ei_w, const float* __restrict__ ei_b,
                 const float* __restrict__ xm_b1, const float* __restrict__ xm_w2,
                 float* __restrict__ mi_f32, float* __restrict__ xout,
                 bf16* __restrict__ mrow, float* __restrict__ dlt) {
  // union: Abuf[2][128*36] (stage-1 staging, dead after stage 1) / Tbuf[128*132]
  __shared__ bf16 smem[128 * 132];
  __shared__ float rxL[128], ryL[128], rzL[128], invdL[128], eijL[128];
  __shared__ float xpart[2][128];
  __shared__ float b1L[HID], b2L[HID], xb1L[HID], eiwL[HID], w2xL[HID];
  __shared__ float eibL;
  bf16* const Abuf = smem;           // 2 x 4608 elements
  bf16* const Tbuf = smem;           // 128 x 132, alive after stage 1

  const int tid = threadIdx.x;
  const int e0  = blockIdx.x * 128;
  if (tid < HID) {
    b1L[tid]  = em_b1[tid];  b2L[tid]  = em_b2[tid];
    xb1L[tid] = xm_b1[tid];  eiwL[tid] = ei_w[tid];  w2xL[tid] = xm_w2[tid];
  }
  if (tid == 0) eibL = ei_b[0];

  const int lane = tid & 63, wv = tid >> 6;
  const int wrow = wv >> 1, wcol = wv & 1;
  const int q = lane >> 4, ml = lane & 15;
  const int mbase = wrow * 64, nbase = wcol * 64;

  const int se = tid >> 1, sh = tid & 1;      // 2 threads per edge row
  const int eg = e0 + se;
  const int sdst = dsti[eg], ssrc = srci[eg];

  // chunk-8 payload: [d_sq | edge_attr(16) | zeros(15)]
  union U16 { bf16 h[16]; uint4 u[2]; } p8;
  {
    const float* ap = eattr + (size_t)eg * 16;
    if (sh == 0) {
      const float* xd = x + 3 * sdst;
      const float* xs = x + 3 * ssrc;
      float dx = xd[0] - xs[0], dy = xd[1] - xs[1], dz = xd[2] - xs[2];
      float dsq = dx * dx + dy * dy + dz * dz;
      rxL[se] = dx; ryL[se] = dy; rzL[se] = dz;
      invdL[se] = 1.f / (sqrtf(dsq + 1e-8f) + 1.f);
      p8.h[0] = __float2bfloat16(dsq);
#pragma unroll
      for (int j = 0; j < 15; ++j) p8.h[1 + j] = __float2bfloat16(ap[j]);
    } else {
      p8.h[0] = __float2bfloat16(ap[15]);
#pragma unroll
      for (int j = 1; j < 16; ++j) p8.h[j] = __float2bfloat16(0.f);
    }
  }

  const f32x4 zf = {0.f, 0.f, 0.f, 0.f};
  f32x4 acc[4][4];
#pragma unroll
  for (int a = 0; a < 4; ++a)
#pragma unroll
    for (int b = 0; b < 4; ++b) acc[a][b] = zf;

  // ---------------- stage 1: t1 = silu(edge_in @ em_w1 + b1), K = 288 ------
  // double-buffered staging, one barrier per chunk
  {
    const bf16* p = hb + (size_t)sdst * HID + sh * 16;
    uint4 a = *(const uint4*)p, b = *(const uint4*)(p + 8);
    bf16* d = Abuf + se * 36 + sh * 16;
    ((uint2*)d)[0] = make_uint2(a.x, a.y);
    ((uint2*)d)[1] = make_uint2(a.z, a.w);
    ((uint2*)d)[2] = make_uint2(b.x, b.y);
    ((uint2*)d)[3] = make_uint2(b.z, b.w);
  }
  __syncthreads();
  for (int c = 0; c < 9; ++c) {
    const int nxt = c + 1;
    uint4 n0, n1;
    if (nxt < 8) {
      const int node = (nxt < 4) ? sdst : ssrc;
      const bf16* p = hb + (size_t)node * HID + (nxt & 3) * 32 + sh * 16;
      n0 = *(const uint4*)p;
      n1 = *(const uint4*)(p + 8);
    } else if (nxt == 8) {
      n0 = p8.u[0]; n1 = p8.u[1];
    }
    const bf16* Ab = Abuf + (c & 1) * 4608;
    s16x8 af[4];
#pragma unroll
    for (int mt = 0; mt < 4; ++mt)
      af[mt] = ld_frag_lds(Ab + (mbase + mt * 16 + ml) * 36 + q * 8);
#pragma unroll
    for (int nt = 0; nt < 4; ++nt) {
      const int n = nbase + nt * 16 + ml;
      s16x8 bfr = ld_frag_g(w1p + (size_t)(c * HID + n) * 32 + q * 8);
#pragma unroll
      for (int mt = 0; mt < 4; ++mt)
        acc[mt][nt] = __builtin_amdgcn_mfma_f32_16x16x32_bf16(af[mt], bfr, acc[mt][nt], 0, 0, 0);
    }
    if (nxt <= 8) {
      bf16* d = Abuf + (nxt & 1) * 4608 + se * 36 + sh * 16;
      ((uint2*)d)[0] = make_uint2(n0.x, n0.y);
      ((uint2*)d)[1] = make_uint2(n0.z, n0.w);
      ((uint2*)d)[2] = make_uint2(n1.x, n1.y);
      ((uint2*)d)[3] = make_uint2(n1.z, n1.w);
    }
    __syncthreads();
  }

  // epilogue 1: silu -> Tbuf (C-layout -> row-major = A-layout for stage 2)
#pragma unroll
  for (int mt = 0; mt < 4; ++mt)
#pragma unroll
    for (int nt = 0; nt < 4; ++nt)
#pragma unroll
      for (int r = 0; r < 4; ++r) {
        int row = mbase + mt * 16 + q * 4 + r;
        int col = nbase + nt * 16 + ml;
        float v = acc[mt][nt][r] + b1L[col];
        v *= sigm(v);
        Tbuf[row * 132 + col] = __float2bfloat16(v);
      }
  __syncthreads();

  // ---------------- stage 2: mij = t1 @ em_w2 + b2, K = 128 ----------------
#pragma unroll
  for (int a = 0; a < 4; ++a)
#pragma unroll
    for (int b = 0; b < 4; ++b) acc[a][b] = zf;
  for (int kc = 0; kc < 4; ++kc) {
    s16x8 af[4];
#pragma unroll
    for (int mt = 0; mt < 4; ++mt)
      af[mt] = ld_frag_lds(Tbuf + (mbase + mt * 16 + ml) * 132 + kc * 32 + q * 8);
#pragma unroll
    for (int nt = 0; nt < 4; ++nt) {
      const int n = nbase + nt * 16 + ml;
      s16x8 bfr = ld_frag_g(w2p + (size_t)(kc * HID + n) * 32 + q * 8);
#pragma unroll
      for (int mt = 0; mt < 4; ++mt)
        acc[mt][nt] = __builtin_amdgcn_mfma_f32_16x16x32_bf16(af[mt], bfr, acc[mt][nt], 0, 0, 0);
    }
  }
  __syncthreads();   // all waves done reading t1 from Tbuf

  // write mij (+b2) into Tbuf
#pragma unroll
  for (int mt = 0; mt < 4; ++mt)
#pragma unroll
    for (int nt = 0; nt < 4; ++nt)
#pragma unroll
      for (int r = 0; r < 4; ++r) {
        int row = mbase + mt * 16 + q * 4 + r;
        int col = nbase + nt * 16 + ml;
        Tbuf[row * 132 + col] = __float2bfloat16(acc[mt][nt][r] + b2L[col]);
      }
  __syncthreads();

  // eij = sigmoid(mij . ei_w + ei_b), 2 threads per edge
  {
    float s = 0.f;
    const bf16* mr = Tbuf + se * 132 + sh * 64;
#pragma unroll
    for (int j = 0; j < 64; ++j) s += __bfloat162float(mr[j]) * eiwL[sh * 64 + j];
    s += __shfl_xor(s, 1);
    if (sh == 0) eijL[se] = sigm(s + eibL);
  }
  __syncthreads();

  if (MODE == 0) {
    // legacy: fp32 atomic scatter into mi
    const float ev = eijL[se];
    float* mp = mi_f32 + (size_t)sdst * HID + sh * 64;
    const bf16* mr = Tbuf + se * 132 + sh * 64;
#pragma unroll
    for (int j = 0; j < 64; ++j)
      unsafeAtomicAdd(mp + j, __bfloat162float(mr[j]) * ev);
  } else {
    // contiguous bf16 row write of mij*eij at original edge position
    const float ev = eijL[se];
    bf16* mp = mrow + (size_t)eg * HID + sh * 64;
    const bf16* tr = Tbuf + se * 132 + sh * 64;
#pragma unroll
    for (int base = 0; base < 64; base += 8) {
      union { uint2 u; unsigned short s[4]; } A, B;
      A.u = *(const uint2*)(tr + base);
      B.u = *(const uint2*)(tr + base + 4);
      union { bf16 h[8]; uint4 u; } o;
#pragma unroll
      for (int k = 0; k < 4; ++k) o.h[k]     = __float2bfloat16(b2f(A.s[k]) * ev);
#pragma unroll
      for (int k = 0; k < 4; ++k) o.h[4 + k] = __float2bfloat16(b2f(B.s[k]) * ev);
      *(uint4*)(mp + base) = o.u;
    }
  }

  // ---------------- x branch: gate = tanh(silu(mij@xm_w1+b) . xm_w2) -------
#pragma unroll
  for (int a = 0; a < 4; ++a)
#pragma unroll
    for (int b = 0; b < 4; ++b) acc[a][b] = zf;
  for (int kc = 0; kc < 4; ++kc) {
    s16x8 af[4];
#pragma unroll
    for (int mt = 0; mt < 4; ++mt)
      af[mt] = ld_frag_lds(Tbuf + (mbase + mt * 16 + ml) * 132 + kc * 32 + q * 8);
#pragma unroll
    for (int nt = 0; nt < 4; ++nt) {
      const int n = nbase + nt * 16 + ml;
      s16x8 bfr = ld_frag_g(xw1p + (size_t)(kc * HID + n) * 32 + q * 8);
#pragma unroll
      for (int mt = 0; mt < 4; ++mt)
        acc[mt][nt] = __builtin_amdgcn_mfma_f32_16x16x32_bf16(af[mt], bfr, acc[mt][nt], 0, 0, 0);
    }
  }
  float part[16];
#pragma unroll
  for (int i = 0; i < 16; ++i) part[i] = 0.f;
#pragma unroll
  for (int mt = 0; mt < 4; ++mt)
#pragma unroll
    for (int nt = 0; nt < 4; ++nt)
#pragma unroll
      for (int r = 0; r < 4; ++r) {
        int col = nbase + nt * 16 + ml;
        float v = acc[mt][nt][r] + xb1L[col];
        v *= sigm(v);
        part[mt * 4 + r] += v * w2xL[col];
      }
#pragma unroll
  for (int i = 0; i < 16; ++i) {
    float v = part[i];
    v += __shfl_xor(v, 1); v += __shfl_xor(v, 2);
    v += __shfl_xor(v, 4); v += __shfl_xor(v, 8);
    if (ml == 0) xpart[wcol][mbase + (i >> 2) * 16 + q * 4 + (i & 3)] = v;
  }
  __syncthreads();
  if (tid < 128) {
    float g  = tanhf(xpart[0][tid] + xpart[1][tid]);
    float sc = invdL[tid] * g;
    if (MODE == 0) {
      int dn = dsti[e0 + tid];
      unsafeAtomicAdd(xout + dn * 3 + 0, rxL[tid] * sc);
      unsafeAtomicAdd(xout + dn * 3 + 1, ryL[tid] * sc);
      unsafeAtomicAdd(xout + dn * 3 + 2, rzL[tid] * sc);
    } else {
      int e = e0 + tid;
      dlt[e * 3 + 0] = rxL[tid] * sc;
      dlt[e * 3 + 1] = ryL[tid] * sc;
      dlt[e * 3 + 2] = rzL[tid] * sc;
    }
  }
}

// ---- segment aggregation: mi[n] = sum mrow[e], xout[n] = x[n] + sum dlt[e] -
__global__ __launch_bounds__(256, 8)
void agg_kernel(const bf16* __restrict__ mrow, const float* __restrict__ dlt,
                const int* __restrict__ ptr, const int* __restrict__ perm,
                const float* __restrict__ x, bf16* __restrict__ mi,
                float* __restrict__ xout) {
  const int wv = threadIdx.x >> 6, lane = threadIdx.x & 63;
  const int n = blockIdx.x * 4 + wv;
  if (n >= N_NODES) return;
  const int p0 = ptr[n], p1 = ptr[n + 1];
  float a0 = 0.f, a1 = 0.f, dacc = 0.f;
  for (int p = p0; p < p1; ++p) {
    const int e = perm[p];
    const unsigned v = *(const unsigned*)(mrow + (size_t)e * HID + lane * 2);
    a0 += __uint_as_float(v << 16);
    a1 += __uint_as_float(v & 0xffff0000u);
    if (lane < 3) dacc += dlt[e * 3 + lane];
  }
  union { bf16 h[2]; unsigned u; } o;
  o.h[0] = __float2bfloat16(a0);
  o.h[1] = __float2bfloat16(a1);
  *(unsigned*)(mi + (size_t)n * HID + lane * 2) = o.u;
  if (lane < 3) xout[n * 3 + lane] = x[n * 3 + lane] + dacc;
}

// ---- node kernel: h_out = h + MLP([mi|h]) ---------------------------------
__global__ __launch_bounds__(256, 2)
void node_kernel(const bf16* __restrict__ mi, const bf16* __restrict__ hb,
                 const float* __restrict__ h,
                 const bf16* __restrict__ nw1p, const bf16* __restrict__ nw2p,
                 const float* __restrict__ nb1, const float* __restrict__ nb2,
                 float* __restrict__ hout) {
  __shared__ bf16 Abuf[128 * 36];
  __shared__ bf16 Tbuf[128 * 132];
  __shared__ float b1L[HID], b2L[HID];
  const int tid = threadIdx.x;
  const int n0 = blockIdx.x * 128;
  if (tid < HID) { b1L[tid] = nb1[tid]; b2L[tid] = nb2[tid]; }
  const int lane = tid & 63, wv = tid >> 6;
  const int wrow = wv >> 1, wcol = wv & 1;
  const int q = lane >> 4, ml = lane & 15;
  const int mbase = wrow * 64, nbase = wcol * 64;
  const int se = tid >> 1, sh = tid & 1;
  int node = n0 + se;
  if (node >= N_NODES) node = 0;   // clamp; stores masked below

  const f32x4 zf = {0.f, 0.f, 0.f, 0.f};
  f32x4 acc[4][4];
#pragma unroll
  for (int a = 0; a < 4; ++a)
#pragma unroll
    for (int b = 0; b < 4; ++b) acc[a][b] = zf;

  for (int c = 0; c < 8; ++c) {    // K = 256: [mi | h], both bf16
    const bf16* p = ((c < 4) ? (mi + (size_t)node * HID + c * 32)
                             : (hb + (size_t)node * HID + (c - 4) * 32)) + sh * 16;
    uint4 v0 = *(const uint4*)p;
    uint4 v1 = *(const uint4*)(p + 8);
    bf16* d = Abuf + se * 36 + sh * 16;
    ((uint2*)d)[0] = make_uint2(v0.x, v0.y);
    ((uint2*)d)[1] = make_uint2(v0.z, v0.w);
    ((uint2*)d)[2] = make_uint2(v1.x, v1.y);
    ((uint2*)d)[3] = make_uint2(v1.z, v1.w);
    __syncthreads();
    s16x8 af[4];
#pragma unroll
    for (int mt = 0; mt < 4; ++mt)
      af[mt] = ld_frag_lds(Abuf + (mbase + mt * 16 + ml) * 36 + q * 8);
#pragma unroll
    for (int nt = 0; nt < 4; ++nt) {
      const int n = nbase + nt * 16 + ml;
      s16x8 bfr = ld_frag_g(nw1p + (size_t)(c * HID + n) * 32 + q * 8);
#pragma unroll
      for (int mt = 0; mt < 4; ++mt)
        acc[mt][nt] = __builtin_amdgcn_mfma_f32_16x16x32_bf16(af[mt], bfr, acc[mt][nt], 0, 0, 0);
    }
    __syncthreads();
  }
#pragma unroll
  for (int mt = 0; mt < 4; ++mt)
#pragma unroll
    for (int nt = 0; nt < 4; ++nt)
#pragma unroll
      for (int r = 0; r < 4; ++r) {
        int row = mbase + mt * 16 + q * 4 + r;
        int col = nbase + nt * 16 + ml;
        float v = acc[mt][nt][r] + b1L[col];
        v *= sigm(v);
        Tbuf[row * 132 + col] = __float2bfloat16(v);
      }
  __syncthreads();
#pragma unroll
  for (int a = 0; a < 4; ++a)
#pragma unroll
    for (int b = 0; b < 4; ++b) acc[a][b] = zf;
  for (int kc = 0; kc < 4; ++kc) {
    s16x8 af[4];
#pragma unroll
    for (int mt = 0; mt < 4; ++mt)
      af[mt] = ld_frag_lds(Tbuf + (mbase + mt * 16 + ml) * 132 + kc * 32 + q * 8);
#pragma unroll
    for (int nt = 0; nt < 4; ++nt) {
      const int n = nbase + nt * 16 + ml;
      s16x8 bfr = ld_frag_g(nw2p + (size_t)(kc * HID + n) * 32 + q * 8);
#pragma unroll
      for (int mt = 0; mt < 4; ++mt)
        acc[mt][nt] = __builtin_amdgcn_mfma_f32_16x16x32_bf16(af[mt], bfr, acc[mt][nt], 0, 0, 0);
    }
  }
#pragma unroll
  for (int mt = 0; mt < 4; ++mt)
#pragma unroll
    for (int nt = 0; nt < 4; ++nt)
#pragma unroll
      for (int r = 0; r < 4; ++r) {
        int row = mbase + mt * 16 + q * 4 + r;
        int nn = n0 + row;
        if (nn < N_NODES) {
          int col = nbase + nt * 16 + ml;
          size_t idx = (size_t)nn * HID + col;
          hout[idx] = h[idx] + acc[mt][nt][r] + b2L[col];
        }
      }
}

// ---- launcher --------------------------------------------------------------
extern "C" void kernel_launch(void* const* d_in, const int* in_sizes, int n_in,
                              void* d_out, int out_size, void* d_ws, size_t ws_size,
                              hipStream_t stream) {
  (void)in_sizes; (void)n_in; (void)out_size;
  const float* h     = (const float*)d_in[0];
  const float* x     = (const float*)d_in[1];
  const int*   eidx  = (const int*)  d_in[2];
  const float* eattr = (const float*)d_in[3];
  const float* em_w1 = (const float*)d_in[4];
  const float* em_b1 = (const float*)d_in[5];
  const float* em_w2 = (const float*)d_in[6];
  const float* em_b2 = (const float*)d_in[7];
  const float* ei_w  = (const float*)d_in[8];
  const float* ei_b  = (const float*)d_in[9];
  const float* xm_w1 = (const float*)d_in[10];
  const float* xm_b1 = (const float*)d_in[11];
  const float* xm_w2 = (const float*)d_in[12];
  const float* nm_w1 = (const float*)d_in[13];
  const float* nm_b1 = (const float*)d_in[14];
  const float* nm_w2 = (const float*)d_in[15];
  const float* nm_b2 = (const float*)d_in[16];

  float* hout = (float*)d_out;
  float* xout = hout + (size_t)N_NODES * HID;

  char* w = (char*)d_ws;
  bf16* hb   = (bf16*)w;  w += (size_t)N_NODES * HID * 2;     // 12.8 MB
  bf16* mi_b = (bf16*)w;  w += (size_t)N_NODES * HID * 2;     // 12.8 MB
  bf16* w1p  = (bf16*)w;  w += 9 * HID * 32 * 2;
  bf16* w2p  = (bf16*)w;  w += 4 * HID * 32 * 2;
  bf16* xw1p = (bf16*)w;  w += 4 * HID * 32 * 2;
  bf16* nw1p = (bf16*)w;  w += 8 * HID * 32 * 2;
  bf16* nw2p = (bf16*)w;  w += 4 * HID * 32 * 2;
  int* cnt   = (int*)w;   w += (size_t)N_NODES * 4;
  int* work  = (int*)w;   w += (size_t)N_NODES * 4;
  int* ptr   = (int*)w;   w += (size_t)(N_NODES + 4) * 4;     // padded to 16B
  int* perm  = (int*)w;   w += (size_t)N_EDGES * 4;
  // branch region (mutually exclusive):
  bf16*  mrow   = (bf16*)w;
  float* dlt    = (float*)(w + (size_t)N_EDGES * HID * 2);
  float* mi_f32 = (float*)w;
  size_t need_sorted = (size_t)(w - (char*)d_ws)
                     + (size_t)N_EDGES * HID * 2 + (size_t)N_EDGES * 3 * 4;
  const bool sorted = (ws_size >= need_sorted);

  cvt_kernel<<<(N_NODES * HID + 255) / 256, 256, 0, stream>>>(h, hb, N_NODES * HID);
  pack_w_kernel<<<(288 * HID + 255) / 256, 256, 0, stream>>>(em_w1, w1p, 273, 288);
  pack_w_kernel<<<(128 * HID + 255) / 256, 256, 0, stream>>>(em_w2, w2p, 128, 128);
  pack_w_kernel<<<(128 * HID + 255) / 256, 256, 0, stream>>>(xm_w1, xw1p, 128, 128);
  pack_w_kernel<<<(256 * HID + 255) / 256, 256, 0, stream>>>(nm_w1, nw1p, 256, 256);
  pack_w_kernel<<<(128 * HID + 255) / 256, 256, 0, stream>>>(nm_w2, nw2p, 128, 128);

  if (sorted) {
    hipMemsetAsync(cnt, 0, (size_t)N_NODES * 4, stream);
    hist_kernel<<<(N_EDGES + 255) / 256, 256, 0, stream>>>(eidx + N_EDGES, cnt);
    scan_kernel<<<1, 1024, 0, stream>>>(cnt, ptr, work);
    scatter_kernel<<<(N_EDGES + 255) / 256, 256, 0, stream>>>(eidx + N_EDGES, work, perm);
    edge_kernel<1><<<N_EDGES / 128, 256, 0, stream>>>(
        hb, x, eidx, eidx + N_EDGES, eattr, w1p, w2p, xw1p,
        em_b1, em_b2, ei_w, ei_b, xm_b1, xm_w2, nullptr, nullptr, mrow, dlt);
    agg_kernel<<<(N_NODES + 3) / 4, 256, 0, stream>>>(mrow, dlt, ptr, perm, x, mi_b, xout);
  } else {
    hipMemsetAsync(mi_f32, 0, (size_t)N_NODES * HID * 4, stream);
    copy_x_kernel<<<(N_NODES * 3 + 255) / 256, 256, 0, stream>>>(x, xout, N_NODES * 3);
    edge_kernel<0><<<N_EDGES / 128, 256, 0, stream>>>(
        hb, x, eidx, eidx + N_EDGES, eattr, w1p, w2p, xw1p,
        em_b1, em_b2, ei_w, ei_b, xm_b1, xm_w2, mi_f32, xout, nullptr, nullptr);
    cvt_kernel<<<(N_NODES * HID + 255) / 256, 256, 0, stream>>>(mi_f32, mi_b, N_NODES * HID);
  }
  node_kernel<<<(N_NODES + 127) / 128, 256, 0, stream>>>(
      mi_b, hb, h, nw1p, nw2p, nm_b1, nm_b2, hout);
}

// Round 3
// 767.593 us; speedup vs baseline: 5.8545x; 1.0305x over previous
//
#include <hip/hip_runtime.h>
#include <hip/hip_bf16.h>

#define N_NODES 50000
#define N_EDGES 640000
#define HID 128

typedef float f32x4 __attribute__((ext_vector_type(4)));
typedef short s16x8 __attribute__((ext_vector_type(8)));
typedef __hip_bfloat16 bf16;

// ---- helpers ---------------------------------------------------------------
__device__ __forceinline__ s16x8 ld_frag_lds(const bf16* p) {
  union { uint2 u[2]; s16x8 v; } r;
  r.u[0] = *(const uint2*)(p);
  r.u[1] = *(const uint2*)(p + 4);
  return r.v;
}
__device__ __forceinline__ s16x8 ld_frag_g(const bf16* p) {
  union { uint4 u; s16x8 v; } r;
  r.u = *(const uint4*)(p);
  return r.v;
}
__device__ __forceinline__ float sigm(float v) { return 1.f / (1.f + __expf(-v)); }
__device__ __forceinline__ float b2f(unsigned short u) {
  return __uint_as_float(((unsigned)u) << 16);
}

// ---- prep kernels ----------------------------------------------------------
__global__ void cvt_kernel(const float* __restrict__ src, bf16* __restrict__ dst, int n) {
  int i = blockIdx.x * 256 + threadIdx.x;
  if (i < n) dst[i] = __float2bfloat16(src[i]);
}
__global__ void copy_x_kernel(const float* __restrict__ src, float* __restrict__ dst, int n) {
  int i = blockIdx.x * 256 + threadIdx.x;
  if (i < n) dst[i] = src[i];
}
// weight [K x 128] fp32 row-major -> bf16 B-fragment order [kc][n][q*8+j]
__global__ void pack_w_kernel(const float* __restrict__ src, bf16* __restrict__ dst,
                              int K, int Kpad) {
  int i = blockIdx.x * 256 + threadIdx.x;
  if (i >= Kpad * HID) return;
  int kk = i & 31;
  int n  = (i >> 5) & 127;
  int kc = i >> 12;
  int k  = kc * 32 + kk;
  float v = (k < K) ? src[(size_t)k * HID + n] : 0.f;
  dst[i] = __float2bfloat16(v);
}

// ---- counting sort (CSR build) ---------------------------------------------
__global__ void hist_kernel(const int* __restrict__ dst, int* __restrict__ cnt) {
  int e = blockIdx.x * 256 + threadIdx.x;
  if (e < N_EDGES) atomicAdd(&cnt[dst[e]], 1);
}
__global__ void scan_kernel(const int* __restrict__ cnt, int* __restrict__ ptr,
                            int* __restrict__ work) {
  __shared__ int sums[1024];
  const int tid = threadIdx.x;
  const int CH = (N_NODES + 1023) / 1024;   // 49
  const int base = tid * CH;
  int s = 0;
  for (int i = 0; i < CH; ++i) { int idx = base + i; if (idx < N_NODES) s += cnt[idx]; }
  sums[tid] = s;
  __syncthreads();
  for (int off = 1; off < 1024; off <<= 1) {
    int v = (tid >= off) ? sums[tid - off] : 0;
    __syncthreads();
    sums[tid] += v;
    __syncthreads();
  }
  int run = (tid == 0) ? 0 : sums[tid - 1];
  for (int i = 0; i < CH; ++i) {
    int idx = base + i;
    if (idx < N_NODES) { ptr[idx] = run; work[idx] = run; run += cnt[idx]; }
  }
  if (tid == 1023) ptr[N_NODES] = sums[1023];
}
__global__ void scatter_kernel(const int* __restrict__ dst, int* __restrict__ work,
                               int* __restrict__ perm) {
  int e = blockIdx.x * 256 + threadIdx.x;
  if (e < N_EDGES) { int p = atomicAdd(&work[dst[e]], 1); perm[p] = e; }
}

// ---- fused edge kernel -----------------------------------------------------
// block = 256 threads (2x2 wave grid), 128 edges/block.
// MODE 0: legacy atomic scatter (fallback). MODE 1: sorted-order row writes —
// block processes edges perm[e0..e0+128) so hi-gathers hit runs of equal dst
// and mrow/dlt land contiguously in sorted position for the streaming agg.
template<int MODE>
__global__ __launch_bounds__(256, 4)
void edge_kernel(const bf16* __restrict__ hb, const float* __restrict__ x,
                 const int* __restrict__ srci, const int* __restrict__ dsti,
                 const int* __restrict__ perm,
                 const float* __restrict__ eattr,
                 const bf16* __restrict__ w1p, const bf16* __restrict__ w2p,
                 const bf16* __restrict__ xw1p,
                 const float* __restrict__ em_b1, const float* __restrict__ em_b2,
                 const float* __restrict__ ei_w, const float* __restrict__ ei_b,
                 const float* __restrict__ xm_b1, const float* __restrict__ xm_w2,
                 float* __restrict__ mi_f32, float* __restrict__ xout,
                 bf16* __restrict__ mrow, float* __restrict__ dlt) {
  // union: Abuf[2][128*36] (stage-1 staging, dead after stage 1) / Tbuf[128*132]
  __shared__ bf16 smem[128 * 132];
  __shared__ float rxL[128], ryL[128], rzL[128], invdL[128], eijL[128];
  __shared__ float xpart[2][128];     // reused: eij partials, then x-gate partials
  __shared__ float b1L[HID], b2L[HID], xb1L[HID], eiwL[HID], w2xL[HID];
  __shared__ float eibL;
  bf16* const Abuf = smem;           // 2 x 4608 elements
  bf16* const Tbuf = smem;           // 128 x 132, alive after stage 1

  const int tid = threadIdx.x;
  const int e0  = blockIdx.x * 128;
  if (tid < HID) {
    b1L[tid]  = em_b1[tid];  b2L[tid]  = em_b2[tid];
    xb1L[tid] = xm_b1[tid];  eiwL[tid] = ei_w[tid];  w2xL[tid] = xm_w2[tid];
  }
  if (tid == 0) eibL = ei_b[0];

  const int lane = tid & 63, wv = tid >> 6;
  const int wrow = wv >> 1, wcol = wv & 1;
  const int q = lane >> 4, ml = lane & 15;
  const int mbase = wrow * 64, nbase = wcol * 64;

  const int se = tid >> 1, sh = tid & 1;      // 2 threads per edge row
  const int pos = e0 + se;                    // sorted position (MODE 1)
  const int eg  = (MODE == 1) ? perm[pos] : pos;
  const int sdst = dsti[eg], ssrc = srci[eg];

  // chunk-8 payload: [d_sq | edge_attr(16) | zeros(15)]
  union U16 { bf16 h[16]; uint4 u[2]; } p8;
  {
    const float* ap = eattr + (size_t)eg * 16;
    if (sh == 0) {
      const float* xd = x + 3 * sdst;
      const float* xs = x + 3 * ssrc;
      float dx = xd[0] - xs[0], dy = xd[1] - xs[1], dz = xd[2] - xs[2];
      float dsq = dx * dx + dy * dy + dz * dz;
      rxL[se] = dx; ryL[se] = dy; rzL[se] = dz;
      invdL[se] = 1.f / (sqrtf(dsq + 1e-8f) + 1.f);
      p8.h[0] = __float2bfloat16(dsq);
#pragma unroll
      for (int j = 0; j < 15; ++j) p8.h[1 + j] = __float2bfloat16(ap[j]);
    } else {
      p8.h[0] = __float2bfloat16(ap[15]);
#pragma unroll
      for (int j = 1; j < 16; ++j) p8.h[j] = __float2bfloat16(0.f);
    }
  }

  const f32x4 zf = {0.f, 0.f, 0.f, 0.f};
  f32x4 acc[4][4];
#pragma unroll
  for (int a = 0; a < 4; ++a)
#pragma unroll
    for (int b = 0; b < 4; ++b) acc[a][b] = zf;

  // ---------------- stage 1: t1 = silu(edge_in @ em_w1 + b1), K = 288 ------
  // double-buffered staging, one barrier per chunk
  {
    const bf16* p = hb + (size_t)sdst * HID + sh * 16;
    uint4 a = *(const uint4*)p, b = *(const uint4*)(p + 8);
    bf16* d = Abuf + se * 36 + sh * 16;
    ((uint2*)d)[0] = make_uint2(a.x, a.y);
    ((uint2*)d)[1] = make_uint2(a.z, a.w);
    ((uint2*)d)[2] = make_uint2(b.x, b.y);
    ((uint2*)d)[3] = make_uint2(b.z, b.w);
  }
  __syncthreads();
  for (int c = 0; c < 9; ++c) {
    const int nxt = c + 1;
    uint4 n0, n1;
    if (nxt < 8) {
      const int node = (nxt < 4) ? sdst : ssrc;
      const bf16* p = hb + (size_t)node * HID + (nxt & 3) * 32 + sh * 16;
      n0 = *(const uint4*)p;
      n1 = *(const uint4*)(p + 8);
    } else if (nxt == 8) {
      n0 = p8.u[0]; n1 = p8.u[1];
    }
    const bf16* Ab = Abuf + (c & 1) * 4608;
    s16x8 af[4];
#pragma unroll
    for (int mt = 0; mt < 4; ++mt)
      af[mt] = ld_frag_lds(Ab + (mbase + mt * 16 + ml) * 36 + q * 8);
#pragma unroll
    for (int nt = 0; nt < 4; ++nt) {
      const int n = nbase + nt * 16 + ml;
      s16x8 bfr = ld_frag_g(w1p + (size_t)(c * HID + n) * 32 + q * 8);
#pragma unroll
      for (int mt = 0; mt < 4; ++mt)
        acc[mt][nt] = __builtin_amdgcn_mfma_f32_16x16x32_bf16(af[mt], bfr, acc[mt][nt], 0, 0, 0);
    }
    if (nxt <= 8) {
      bf16* d = Abuf + (nxt & 1) * 4608 + se * 36 + sh * 16;
      ((uint2*)d)[0] = make_uint2(n0.x, n0.y);
      ((uint2*)d)[1] = make_uint2(n0.z, n0.w);
      ((uint2*)d)[2] = make_uint2(n1.x, n1.y);
      ((uint2*)d)[3] = make_uint2(n1.z, n1.w);
    }
    __syncthreads();
  }

  // epilogue 1: silu -> Tbuf (C-layout -> row-major = A-layout for stage 2)
#pragma unroll
  for (int mt = 0; mt < 4; ++mt)
#pragma unroll
    for (int nt = 0; nt < 4; ++nt)
#pragma unroll
      for (int r = 0; r < 4; ++r) {
        int row = mbase + mt * 16 + q * 4 + r;
        int col = nbase + nt * 16 + ml;
        float v = acc[mt][nt][r] + b1L[col];
        v *= sigm(v);
        Tbuf[row * 132 + col] = __float2bfloat16(v);
      }
  __syncthreads();

  // ---------------- stage 2: mij = t1 @ em_w2 + b2, K = 128 ----------------
#pragma unroll
  for (int a = 0; a < 4; ++a)
#pragma unroll
    for (int b = 0; b < 4; ++b) acc[a][b] = zf;
  for (int kc = 0; kc < 4; ++kc) {
    s16x8 af[4];
#pragma unroll
    for (int mt = 0; mt < 4; ++mt)
      af[mt] = ld_frag_lds(Tbuf + (mbase + mt * 16 + ml) * 132 + kc * 32 + q * 8);
#pragma unroll
    for (int nt = 0; nt < 4; ++nt) {
      const int n = nbase + nt * 16 + ml;
      s16x8 bfr = ld_frag_g(w2p + (size_t)(kc * HID + n) * 32 + q * 8);
#pragma unroll
      for (int mt = 0; mt < 4; ++mt)
        acc[mt][nt] = __builtin_amdgcn_mfma_f32_16x16x32_bf16(af[mt], bfr, acc[mt][nt], 0, 0, 0);
    }
  }
  // mijf = acc + b2 (in place, fp32); eij partials in registers (no LDS GEMV)
  {
    float part[16];
#pragma unroll
    for (int i = 0; i < 16; ++i) part[i] = 0.f;
#pragma unroll
    for (int mt = 0; mt < 4; ++mt)
#pragma unroll
      for (int nt = 0; nt < 4; ++nt) {
        int col = nbase + nt * 16 + ml;
#pragma unroll
        for (int r = 0; r < 4; ++r) {
          float v = acc[mt][nt][r] + b2L[col];
          acc[mt][nt][r] = v;
          part[mt * 4 + r] += v * eiwL[col];
        }
      }
#pragma unroll
    for (int i = 0; i < 16; ++i) {
      float v = part[i];
      v += __shfl_xor(v, 1); v += __shfl_xor(v, 2);
      v += __shfl_xor(v, 4); v += __shfl_xor(v, 8);
      if (ml == 0) xpart[wcol][mbase + (i >> 2) * 16 + q * 4 + (i & 3)] = v;
    }
  }
  __syncthreads();   // t1 reads done, eij partials visible

  // write mij into Tbuf; finalize eij
#pragma unroll
  for (int mt = 0; mt < 4; ++mt)
#pragma unroll
    for (int nt = 0; nt < 4; ++nt)
#pragma unroll
      for (int r = 0; r < 4; ++r) {
        int row = mbase + mt * 16 + q * 4 + r;
        int col = nbase + nt * 16 + ml;
        Tbuf[row * 132 + col] = __float2bfloat16(acc[mt][nt][r]);
      }
  if (tid < 128) eijL[tid] = sigm(xpart[0][tid] + xpart[1][tid] + eibL);
  __syncthreads();

  if (MODE == 0) {
    // legacy: fp32 atomic scatter into mi
    const float ev = eijL[se];
    float* mp = mi_f32 + (size_t)sdst * HID + sh * 64;
    const bf16* mr = Tbuf + se * 132 + sh * 64;
#pragma unroll
    for (int j = 0; j < 64; ++j)
      unsafeAtomicAdd(mp + j, __bfloat162float(mr[j]) * ev);
  } else {
    // contiguous bf16 row write of mij*eij at SORTED position
    const float ev = eijL[se];
    bf16* mp = mrow + (size_t)pos * HID + sh * 64;
    const bf16* tr = Tbuf + se * 132 + sh * 64;
#pragma unroll
    for (int base = 0; base < 64; base += 8) {
      union { uint2 u; unsigned short s[4]; } A, B;
      A.u = *(const uint2*)(tr + base);
      B.u = *(const uint2*)(tr + base + 4);
      union { bf16 h[8]; uint4 u; } o;
#pragma unroll
      for (int k = 0; k < 4; ++k) o.h[k]     = __float2bfloat16(b2f(A.s[k]) * ev);
#pragma unroll
      for (int k = 0; k < 4; ++k) o.h[4 + k] = __float2bfloat16(b2f(B.s[k]) * ev);
      *(uint4*)(mp + base) = o.u;
    }
  }

  // ---------------- x branch: gate = tanh(silu(mij@xm_w1+b) . xm_w2) -------
#pragma unroll
  for (int a = 0; a < 4; ++a)
#pragma unroll
    for (int b = 0; b < 4; ++b) acc[a][b] = zf;
  for (int kc = 0; kc < 4; ++kc) {
    s16x8 af[4];
#pragma unroll
    for (int mt = 0; mt < 4; ++mt)
      af[mt] = ld_frag_lds(Tbuf + (mbase + mt * 16 + ml) * 132 + kc * 32 + q * 8);
#pragma unroll
    for (int nt = 0; nt < 4; ++nt) {
      const int n = nbase + nt * 16 + ml;
      s16x8 bfr = ld_frag_g(xw1p + (size_t)(kc * HID + n) * 32 + q * 8);
#pragma unroll
      for (int mt = 0; mt < 4; ++mt)
        acc[mt][nt] = __builtin_amdgcn_mfma_f32_16x16x32_bf16(af[mt], bfr, acc[mt][nt], 0, 0, 0);
    }
  }
  float part[16];
#pragma unroll
  for (int i = 0; i < 16; ++i) part[i] = 0.f;
#pragma unroll
  for (int mt = 0; mt < 4; ++mt)
#pragma unroll
    for (int nt = 0; nt < 4; ++nt)
#pragma unroll
      for (int r = 0; r < 4; ++r) {
        int col = nbase + nt * 16 + ml;
        float v = acc[mt][nt][r] + xb1L[col];
        v *= sigm(v);
        part[mt * 4 + r] += v * w2xL[col];
      }
#pragma unroll
  for (int i = 0; i < 16; ++i) {
    float v = part[i];
    v += __shfl_xor(v, 1); v += __shfl_xor(v, 2);
    v += __shfl_xor(v, 4); v += __shfl_xor(v, 8);
    if (ml == 0) xpart[wcol][mbase + (i >> 2) * 16 + q * 4 + (i & 3)] = v;
  }
  __syncthreads();
  if (tid < 128) {
    float g  = tanhf(xpart[0][tid] + xpart[1][tid]);
    float sc = invdL[tid] * g;
    if (MODE == 0) {
      int dn = dsti[e0 + tid];
      unsafeAtomicAdd(xout + dn * 3 + 0, rxL[tid] * sc);
      unsafeAtomicAdd(xout + dn * 3 + 1, ryL[tid] * sc);
      unsafeAtomicAdd(xout + dn * 3 + 2, rzL[tid] * sc);
    } else {
      int p = e0 + tid;      // sorted position
      dlt[p * 3 + 0] = rxL[tid] * sc;
      dlt[p * 3 + 1] = ryL[tid] * sc;
      dlt[p * 3 + 2] = rzL[tid] * sc;
    }
  }
}

// ---- segment aggregation (streaming, sorted rows) --------------------------
__global__ __launch_bounds__(256, 8)
void agg_kernel(const bf16* __restrict__ mrow, const float* __restrict__ dlt,
                const int* __restrict__ ptr,
                const float* __restrict__ x, bf16* __restrict__ mi,
                float* __restrict__ xout) {
  const int wv = threadIdx.x >> 6, lane = threadIdx.x & 63;
  const int n = blockIdx.x * 4 + wv;
  if (n >= N_NODES) return;
  const int p0 = ptr[n], p1 = ptr[n + 1];
  float a0 = 0.f, a1 = 0.f, dacc = 0.f;
  for (int p = p0; p < p1; ++p) {
    const unsigned v = *(const unsigned*)(mrow + (size_t)p * HID + lane * 2);
    a0 += __uint_as_float(v << 16);
    a1 += __uint_as_float(v & 0xffff0000u);
    if (lane < 3) dacc += dlt[p * 3 + lane];
  }
  union { bf16 h[2]; unsigned u; } o;
  o.h[0] = __float2bfloat16(a0);
  o.h[1] = __float2bfloat16(a1);
  *(unsigned*)(mi + (size_t)n * HID + lane * 2) = o.u;
  if (lane < 3) xout[n * 3 + lane] = x[n * 3 + lane] + dacc;
}

// ---- node kernel: h_out = h + MLP([mi|h]) ---------------------------------
__global__ __launch_bounds__(256, 2)
void node_kernel(const bf16* __restrict__ mi, const bf16* __restrict__ hb,
                 const float* __restrict__ h,
                 const bf16* __restrict__ nw1p, const bf16* __restrict__ nw2p,
                 const float* __restrict__ nb1, const float* __restrict__ nb2,
                 float* __restrict__ hout) {
  __shared__ bf16 Abuf[128 * 36];
  __shared__ bf16 Tbuf[128 * 132];
  __shared__ float b1L[HID], b2L[HID];
  const int tid = threadIdx.x;
  const int n0 = blockIdx.x * 128;
  if (tid < HID) { b1L[tid] = nb1[tid]; b2L[tid] = nb2[tid]; }
  const int lane = tid & 63, wv = tid >> 6;
  const int wrow = wv >> 1, wcol = wv & 1;
  const int q = lane >> 4, ml = lane & 15;
  const int mbase = wrow * 64, nbase = wcol * 64;
  const int se = tid >> 1, sh = tid & 1;
  int node = n0 + se;
  if (node >= N_NODES) node = 0;   // clamp; stores masked below

  const f32x4 zf = {0.f, 0.f, 0.f, 0.f};
  f32x4 acc[4][4];
#pragma unroll
  for (int a = 0; a < 4; ++a)
#pragma unroll
    for (int b = 0; b < 4; ++b) acc[a][b] = zf;

  for (int c = 0; c < 8; ++c) {    // K = 256: [mi | h], both bf16
    const bf16* p = ((c < 4) ? (mi + (size_t)node * HID + c * 32)
                             : (hb + (size_t)node * HID + (c - 4) * 32)) + sh * 16;
    uint4 v0 = *(const uint4*)p;
    uint4 v1 = *(const uint4*)(p + 8);
    bf16* d = Abuf + se * 36 + sh * 16;
    ((uint2*)d)[0] = make_uint2(v0.x, v0.y);
    ((uint2*)d)[1] = make_uint2(v0.z, v0.w);
    ((uint2*)d)[2] = make_uint2(v1.x, v1.y);
    ((uint2*)d)[3] = make_uint2(v1.z, v1.w);
    __syncthreads();
    s16x8 af[4];
#pragma unroll
    for (int mt = 0; mt < 4; ++mt)
      af[mt] = ld_frag_lds(Abuf + (mbase + mt * 16 + ml) * 36 + q * 8);
#pragma unroll
    for (int nt = 0; nt < 4; ++nt) {
      const int n = nbase + nt * 16 + ml;
      s16x8 bfr = ld_frag_g(nw1p + (size_t)(c * HID + n) * 32 + q * 8);
#pragma unroll
      for (int mt = 0; mt < 4; ++mt)
        acc[mt][nt] = __builtin_amdgcn_mfma_f32_16x16x32_bf16(af[mt], bfr, acc[mt][nt], 0, 0, 0);
    }
    __syncthreads();
  }
#pragma unroll
  for (int mt = 0; mt < 4; ++mt)
#pragma unroll
    for (int nt = 0; nt < 4; ++nt)
#pragma unroll
      for (int r = 0; r < 4; ++r) {
        int row = mbase + mt * 16 + q * 4 + r;
        int col = nbase + nt * 16 + ml;
        float v = acc[mt][nt][r] + b1L[col];
        v *= sigm(v);
        Tbuf[row * 132 + col] = __float2bfloat16(v);
      }
  __syncthreads();
#pragma unroll
  for (int a = 0; a < 4; ++a)
#pragma unroll
    for (int b = 0; b < 4; ++b) acc[a][b] = zf;
  for (int kc = 0; kc < 4; ++kc) {
    s16x8 af[4];
#pragma unroll
    for (int mt = 0; mt < 4; ++mt)
      af[mt] = ld_frag_lds(Tbuf + (mbase + mt * 16 + ml) * 132 + kc * 32 + q * 8);
#pragma unroll
    for (int nt = 0; nt < 4; ++nt) {
      const int n = nbase + nt * 16 + ml;
      s16x8 bfr = ld_frag_g(nw2p + (size_t)(kc * HID + n) * 32 + q * 8);
#pragma unroll
      for (int mt = 0; mt < 4; ++mt)
        acc[mt][nt] = __builtin_amdgcn_mfma_f32_16x16x32_bf16(af[mt], bfr, acc[mt][nt], 0, 0, 0);
    }
  }
#pragma unroll
  for (int mt = 0; mt < 4; ++mt)
#pragma unroll
    for (int nt = 0; nt < 4; ++nt)
#pragma unroll
      for (int r = 0; r < 4; ++r) {
        int row = mbase + mt * 16 + q * 4 + r;
        int nn = n0 + row;
        if (nn < N_NODES) {
          int col = nbase + nt * 16 + ml;
          size_t idx = (size_t)nn * HID + col;
          hout[idx] = h[idx] + acc[mt][nt][r] + b2L[col];
        }
      }
}

// ---- launcher --------------------------------------------------------------
extern "C" void kernel_launch(void* const* d_in, const int* in_sizes, int n_in,
                              void* d_out, int out_size, void* d_ws, size_t ws_size,
                              hipStream_t stream) {
  (void)in_sizes; (void)n_in; (void)out_size;
  const float* h     = (const float*)d_in[0];
  const float* x     = (const float*)d_in[1];
  const int*   eidx  = (const int*)  d_in[2];
  const float* eattr = (const float*)d_in[3];
  const float* em_w1 = (const float*)d_in[4];
  const float* em_b1 = (const float*)d_in[5];
  const float* em_w2 = (const float*)d_in[6];
  const float* em_b2 = (const float*)d_in[7];
  const float* ei_w  = (const float*)d_in[8];
  const float* ei_b  = (const float*)d_in[9];
  const float* xm_w1 = (const float*)d_in[10];
  const float* xm_b1 = (const float*)d_in[11];
  const float* xm_w2 = (const float*)d_in[12];
  const float* nm_w1 = (const float*)d_in[13];
  const float* nm_b1 = (const float*)d_in[14];
  const float* nm_w2 = (const float*)d_in[15];
  const float* nm_b2 = (const float*)d_in[16];

  float* hout = (float*)d_out;
  float* xout = hout + (size_t)N_NODES * HID;

  char* w = (char*)d_ws;
  bf16* hb   = (bf16*)w;  w += (size_t)N_NODES * HID * 2;     // 12.8 MB
  bf16* mi_b = (bf16*)w;  w += (size_t)N_NODES * HID * 2;     // 12.8 MB
  bf16* w1p  = (bf16*)w;  w += 9 * HID * 32 * 2;
  bf16* w2p  = (bf16*)w;  w += 4 * HID * 32 * 2;
  bf16* xw1p = (bf16*)w;  w += 4 * HID * 32 * 2;
  bf16* nw1p = (bf16*)w;  w += 8 * HID * 32 * 2;
  bf16* nw2p = (bf16*)w;  w += 4 * HID * 32 * 2;
  int* cnt   = (int*)w;   w += (size_t)N_NODES * 4;
  int* work  = (int*)w;   w += (size_t)N_NODES * 4;
  int* ptr   = (int*)w;   w += (size_t)(N_NODES + 4) * 4;     // padded to 16B
  int* perm  = (int*)w;   w += (size_t)N_EDGES * 4;
  // branch region (mutually exclusive):
  bf16*  mrow   = (bf16*)w;
  float* dlt    = (float*)(w + (size_t)N_EDGES * HID * 2);
  float* mi_f32 = (float*)w;
  size_t need_sorted = (size_t)(w - (char*)d_ws)
                     + (size_t)N_EDGES * HID * 2 + (size_t)N_EDGES * 3 * 4;
  const bool sorted = (ws_size >= need_sorted);

  cvt_kernel<<<(N_NODES * HID + 255) / 256, 256, 0, stream>>>(h, hb, N_NODES * HID);
  pack_w_kernel<<<(288 * HID + 255) / 256, 256, 0, stream>>>(em_w1, w1p, 273, 288);
  pack_w_kernel<<<(128 * HID + 255) / 256, 256, 0, stream>>>(em_w2, w2p, 128, 128);
  pack_w_kernel<<<(128 * HID + 255) / 256, 256, 0, stream>>>(xm_w1, xw1p, 128, 128);
  pack_w_kernel<<<(256 * HID + 255) / 256, 256, 0, stream>>>(nm_w1, nw1p, 256, 256);
  pack_w_kernel<<<(128 * HID + 255) / 256, 256, 0, stream>>>(nm_w2, nw2p, 128, 128);

  if (sorted) {
    hipMemsetAsync(cnt, 0, (size_t)N_NODES * 4, stream);
    hist_kernel<<<(N_EDGES + 255) / 256, 256, 0, stream>>>(eidx + N_EDGES, cnt);
    scan_kernel<<<1, 1024, 0, stream>>>(cnt, ptr, work);
    scatter_kernel<<<(N_EDGES + 255) / 256, 256, 0, stream>>>(eidx + N_EDGES, work, perm);
    edge_kernel<1><<<N_EDGES / 128, 256, 0, stream>>>(
        hb, x, eidx, eidx + N_EDGES, perm, eattr, w1p, w2p, xw1p,
        em_b1, em_b2, ei_w, ei_b, xm_b1, xm_w2, nullptr, nullptr, mrow, dlt);
    agg_kernel<<<(N_NODES + 3) / 4, 256, 0, stream>>>(mrow, dlt, ptr, x, mi_b, xout);
  } else {
    hipMemsetAsync(mi_f32, 0, (size_t)N_NODES * HID * 4, stream);
    copy_x_kernel<<<(N_NODES * 3 + 255) / 256, 256, 0, stream>>>(x, xout, N_NODES * 3);
    edge_kernel<0><<<N_EDGES / 128, 256, 0, stream>>>(
        hb, x, eidx, eidx + N_EDGES, nullptr, eattr, w1p, w2p, xw1p,
        em_b1, em_b2, ei_w, ei_b, xm_b1, xm_w2, mi_f32, xout, nullptr, nullptr);
    cvt_kernel<<<(N_NODES * HID + 255) / 256, 256, 0, stream>>>(mi_f32, mi_b, N_NODES * HID);
  }
  node_kernel<<<(N_NODES + 127) / 128, 256, 0, stream>>>(
      mi_b, hb, h, nw1p, nw2p, nm_b1, nm_b2, hout);
}

// Round 4
// 562.494 us; speedup vs baseline: 7.9891x; 1.3646x over previous
//
#include <hip/hip_runtime.h>
#include <hip/hip_bf16.h>

#define N_NODES 50000
#define N_EDGES 640000
#define HID 128

typedef float f32x4 __attribute__((ext_vector_type(4)));
typedef short s16x8 __attribute__((ext_vector_type(8)));
typedef __hip_bfloat16 bf16;

// ---- helpers ---------------------------------------------------------------
__device__ __forceinline__ s16x8 ld_frag_lds(const bf16* p) {
  union { uint2 u[2]; s16x8 v; } r;
  r.u[0] = *(const uint2*)(p);
  r.u[1] = *(const uint2*)(p + 4);
  return r.v;
}
__device__ __forceinline__ s16x8 ld_frag_g(const bf16* p) {
  union { uint4 u; s16x8 v; } r;
  r.u = *(const uint4*)(p);
  return r.v;
}
__device__ __forceinline__ float sigm(float v) { return 1.f / (1.f + __expf(-v)); }
__device__ __forceinline__ float b2f(unsigned short u) {
  return __uint_as_float(((unsigned)u) << 16);
}

// ---- prep kernels ----------------------------------------------------------
__global__ void cvt_kernel(const float* __restrict__ src, bf16* __restrict__ dst, int n) {
  int i = blockIdx.x * 256 + threadIdx.x;
  if (i < n) dst[i] = __float2bfloat16(src[i]);
}
__global__ void copy_x_kernel(const float* __restrict__ src, float* __restrict__ dst, int n) {
  int i = blockIdx.x * 256 + threadIdx.x;
  if (i < n) dst[i] = src[i];
}
// all 5 weights packed in one dispatch: fp32 [K x 128] -> bf16 B-frag [kc][n][q*8+j]
__device__ __forceinline__ void pack_one(const float* __restrict__ src,
                                         bf16* __restrict__ dst, int K, int i) {
  int kk = i & 31;
  int n  = (i >> 5) & 127;
  int kc = i >> 12;
  int k  = kc * 32 + kk;
  float v = (k < K) ? src[(size_t)k * HID + n] : 0.f;
  dst[i] = __float2bfloat16(v);
}
__global__ void pack_all_kernel(const float* __restrict__ em_w1, const float* __restrict__ em_w2,
                                const float* __restrict__ xm_w1, const float* __restrict__ nm_w1,
                                const float* __restrict__ nm_w2,
                                bf16* __restrict__ w1p, bf16* __restrict__ w2p,
                                bf16* __restrict__ xw1p, bf16* __restrict__ nw1p,
                                bf16* __restrict__ nw2p) {
  int gid = blockIdx.x * 256 + threadIdx.x;
  if      (gid < 36864)  pack_one(em_w1, w1p,  273, gid);
  else if (gid < 53248)  pack_one(em_w2, w2p,  128, gid - 36864);
  else if (gid < 69632)  pack_one(xm_w1, xw1p, 128, gid - 53248);
  else if (gid < 102400) pack_one(nm_w1, nw1p, 256, gid - 69632);
  else if (gid < 118784) pack_one(nm_w2, nw2p, 128, gid - 102400);
}

// ---- counting sort (CSR build) ---------------------------------------------
__global__ void hist_kernel(const int* __restrict__ dst, int* __restrict__ cnt) {
  int e = blockIdx.x * 256 + threadIdx.x;
  if (e < N_EDGES) atomicAdd(&cnt[dst[e]], 1);
}
// 3-phase parallel exclusive scan over cnt -> ptr (+ work copy)
__global__ void scanA_kernel(const int* __restrict__ cnt, int* __restrict__ ptr,
                             int* __restrict__ bsum) {
  __shared__ int s[256];
  const int tid = threadIdx.x;
  const int i = blockIdx.x * 256 + tid;
  int v = (i < N_NODES) ? cnt[i] : 0;
  s[tid] = v;
  __syncthreads();
  for (int off = 1; off < 256; off <<= 1) {
    int t = (tid >= off) ? s[tid - off] : 0;
    __syncthreads();
    s[tid] += t;
    __syncthreads();
  }
  if (i < N_NODES) ptr[i] = s[tid] - v;
  if (tid == 255) bsum[blockIdx.x] = s[255];
}
__global__ void scanB_kernel(const int* __restrict__ bsum, int* __restrict__ boff, int nb) {
  __shared__ int s[256];
  const int tid = threadIdx.x;
  int v = (tid < nb) ? bsum[tid] : 0;
  s[tid] = v;
  __syncthreads();
  for (int off = 1; off < 256; off <<= 1) {
    int t = (tid >= off) ? s[tid - off] : 0;
    __syncthreads();
    s[tid] += t;
    __syncthreads();
  }
  if (tid < nb) boff[tid] = s[tid] - v;
  if (tid == nb - 1) boff[nb] = s[tid];
}
__global__ void scanC_kernel(int* __restrict__ ptr, int* __restrict__ work,
                             const int* __restrict__ boff, int nb) {
  const int i = blockIdx.x * 256 + threadIdx.x;
  if (i < N_NODES) {
    int p = ptr[i] + boff[blockIdx.x];
    ptr[i] = p;
    work[i] = p;
  }
  if (blockIdx.x == 0 && threadIdx.x == 0) ptr[N_NODES] = boff[nb];
}
__global__ void scatter_kernel(const int* __restrict__ dst, int* __restrict__ work,
                               int* __restrict__ perm) {
  int e = blockIdx.x * 256 + threadIdx.x;
  if (e < N_EDGES) { int p = atomicAdd(&work[dst[e]], 1); perm[p] = e; }
}

// ---- fused edge kernel -----------------------------------------------------
// 256 threads (2x2 wave grid), 128 sorted edges/block.
// MODE 0: legacy atomic scatter (fallback). MODE 1: in-block segmented reduce,
// interior segments store mi/xout directly; boundary partials -> records.
template<int MODE>
__global__ __launch_bounds__(256, 4)
void edge_kernel(const bf16* __restrict__ hb, const float* __restrict__ x,
                 const int* __restrict__ srci, const int* __restrict__ dsti,
                 const int* __restrict__ perm, const int* __restrict__ ptr,
                 const float* __restrict__ eattr,
                 const bf16* __restrict__ w1p, const bf16* __restrict__ w2p,
                 const bf16* __restrict__ xw1p,
                 const float* __restrict__ em_b1, const float* __restrict__ em_b2,
                 const float* __restrict__ ei_w, const float* __restrict__ ei_b,
                 const float* __restrict__ xm_b1, const float* __restrict__ xm_w2,
                 float* __restrict__ mi_f32, float* __restrict__ xout,
                 bf16* __restrict__ mi_b,
                 float* __restrict__ headrec, float* __restrict__ tailrec,
                 float* __restrict__ headx, float* __restrict__ tailx) {
  // LDS arena, lifetime-overlaid (40496 B -> 4 blocks/CU)
  __shared__ float arena[10124];
  bf16*  const smem  = (bf16*)arena;       // Abuf (2x4608) then Tbuf (128x132)
  float* const rxL   = arena + 8448;
  float* const ryL   = arena + 8576;
  float* const rzL   = arena + 8704;
  float* const invdL = arena + 8832;
  float* const eijL  = arena + 8960;
  float* const b1L   = arena + 9088;
  float* const b2L   = arena + 9216;
  float* const xb1L  = arena + 9344;
  float* const eiwL  = arena + 9472;
  float* const w2xL  = arena + 9600;
  float* const eibL  = arena + 9728;
  float* const xpart = arena + 9736;               // [2][128], two lifetimes
  int*   const segstart = (int*)(arena + 9736);    // overlay after xpart dies
  int*   const segmode  = (int*)(arena + 9736) + 129;
  int*   const nsegA_p  = (int*)(arena + 9736) + 257;
  int*   const nseg_p   = (int*)(arena + 9736) + 258;
  int*   const dstL  = (int*)(arena + 9996);       // [128]
  bf16*  const Abuf = smem;
  bf16*  const Tbuf = smem;

  const int tid = threadIdx.x;
  const int e0  = blockIdx.x * 128;
  if (tid < HID) {
    b1L[tid]  = em_b1[tid];  b2L[tid]  = em_b2[tid];
    xb1L[tid] = xm_b1[tid];  eiwL[tid] = ei_w[tid];  w2xL[tid] = xm_w2[tid];
  }
  if (tid == 0) eibL[0] = ei_b[0];

  const int lane = tid & 63, wv = tid >> 6;
  const int wrow = wv >> 1, wcol = wv & 1;
  const int q = lane >> 4, ml = lane & 15;
  const int mbase = wrow * 64, nbase = wcol * 64;

  const int se = tid >> 1, sh = tid & 1;      // 2 threads per edge row
  const int pos = e0 + se;                    // sorted position (MODE 1)
  const int eg  = (MODE == 1) ? perm[pos] : pos;
  const int sdst = dsti[eg], ssrc = srci[eg];
  if (sh == 0) dstL[se] = sdst;

  // chunk-8 payload: [d_sq | edge_attr(16) | zeros(15)]
  union U16 { bf16 h[16]; uint4 u[2]; } p8;
  {
    const float* ap = eattr + (size_t)eg * 16;
    if (sh == 0) {
      const float* xd = x + 3 * sdst;
      const float* xs = x + 3 * ssrc;
      float dx = xd[0] - xs[0], dy = xd[1] - xs[1], dz = xd[2] - xs[2];
      float dsq = dx * dx + dy * dy + dz * dz;
      rxL[se] = dx; ryL[se] = dy; rzL[se] = dz;
      invdL[se] = 1.f / (sqrtf(dsq + 1e-8f) + 1.f);
      p8.h[0] = __float2bfloat16(dsq);
#pragma unroll
      for (int j = 0; j < 15; ++j) p8.h[1 + j] = __float2bfloat16(ap[j]);
    } else {
      p8.h[0] = __float2bfloat16(ap[15]);
#pragma unroll
      for (int j = 1; j < 16; ++j) p8.h[j] = __float2bfloat16(0.f);
    }
  }

  const f32x4 zf = {0.f, 0.f, 0.f, 0.f};
  f32x4 acc[4][4];
#pragma unroll
  for (int a = 0; a < 4; ++a)
#pragma unroll
    for (int b = 0; b < 4; ++b) acc[a][b] = zf;

  // ---------------- stage 1: t1 = silu(edge_in @ em_w1 + b1), K = 288 ------
  {
    const bf16* p = hb + (size_t)sdst * HID + sh * 16;
    uint4 a = *(const uint4*)p, b = *(const uint4*)(p + 8);
    bf16* d = Abuf + se * 36 + sh * 16;
    ((uint2*)d)[0] = make_uint2(a.x, a.y);
    ((uint2*)d)[1] = make_uint2(a.z, a.w);
    ((uint2*)d)[2] = make_uint2(b.x, b.y);
    ((uint2*)d)[3] = make_uint2(b.z, b.w);
  }
  __syncthreads();
  for (int c = 0; c < 9; ++c) {
    const int nxt = c + 1;
    uint4 n0, n1;
    if (nxt < 8) {
      const int node = (nxt < 4) ? sdst : ssrc;
      const bf16* p = hb + (size_t)node * HID + (nxt & 3) * 32 + sh * 16;
      n0 = *(const uint4*)p;
      n1 = *(const uint4*)(p + 8);
    } else if (nxt == 8) {
      n0 = p8.u[0]; n1 = p8.u[1];
    }
    const bf16* Ab = Abuf + (c & 1) * 4608;
    s16x8 af[4];
#pragma unroll
    for (int mt = 0; mt < 4; ++mt)
      af[mt] = ld_frag_lds(Ab + (mbase + mt * 16 + ml) * 36 + q * 8);
#pragma unroll
    for (int nt = 0; nt < 4; ++nt) {
      const int n = nbase + nt * 16 + ml;
      s16x8 bfr = ld_frag_g(w1p + (size_t)(c * HID + n) * 32 + q * 8);
#pragma unroll
      for (int mt = 0; mt < 4; ++mt)
        acc[mt][nt] = __builtin_amdgcn_mfma_f32_16x16x32_bf16(af[mt], bfr, acc[mt][nt], 0, 0, 0);
    }
    if (nxt <= 8) {
      bf16* d = Abuf + (nxt & 1) * 4608 + se * 36 + sh * 16;
      ((uint2*)d)[0] = make_uint2(n0.x, n0.y);
      ((uint2*)d)[1] = make_uint2(n0.z, n0.w);
      ((uint2*)d)[2] = make_uint2(n1.x, n1.y);
      ((uint2*)d)[3] = make_uint2(n1.z, n1.w);
    }
    __syncthreads();
  }

  // epilogue 1: silu -> Tbuf
#pragma unroll
  for (int mt = 0; mt < 4; ++mt)
#pragma unroll
    for (int nt = 0; nt < 4; ++nt)
#pragma unroll
      for (int r = 0; r < 4; ++r) {
        int row = mbase + mt * 16 + q * 4 + r;
        int col = nbase + nt * 16 + ml;
        float v = acc[mt][nt][r] + b1L[col];
        v *= sigm(v);
        Tbuf[row * 132 + col] = __float2bfloat16(v);
      }
  __syncthreads();

  // ---------------- stage 2: mij = t1 @ em_w2 + b2, K = 128 ----------------
#pragma unroll
  for (int a = 0; a < 4; ++a)
#pragma unroll
    for (int b = 0; b < 4; ++b) acc[a][b] = zf;
  for (int kc = 0; kc < 4; ++kc) {
    s16x8 af[4];
#pragma unroll
    for (int mt = 0; mt < 4; ++mt)
      af[mt] = ld_frag_lds(Tbuf + (mbase + mt * 16 + ml) * 132 + kc * 32 + q * 8);
#pragma unroll
    for (int nt = 0; nt < 4; ++nt) {
      const int n = nbase + nt * 16 + ml;
      s16x8 bfr = ld_frag_g(w2p + (size_t)(kc * HID + n) * 32 + q * 8);
#pragma unroll
      for (int mt = 0; mt < 4; ++mt)
        acc[mt][nt] = __builtin_amdgcn_mfma_f32_16x16x32_bf16(af[mt], bfr, acc[mt][nt], 0, 0, 0);
    }
  }
  // add b2 in regs; eij partials in regs -> xpart
  {
    float part[16];
#pragma unroll
    for (int i = 0; i < 16; ++i) part[i] = 0.f;
#pragma unroll
    for (int mt = 0; mt < 4; ++mt)
#pragma unroll
      for (int nt = 0; nt < 4; ++nt) {
        int col = nbase + nt * 16 + ml;
#pragma unroll
        for (int r = 0; r < 4; ++r) {
          float v = acc[mt][nt][r] + b2L[col];
          acc[mt][nt][r] = v;
          part[mt * 4 + r] += v * eiwL[col];
        }
      }
#pragma unroll
    for (int i = 0; i < 16; ++i) {
      float v = part[i];
      v += __shfl_xor(v, 1); v += __shfl_xor(v, 2);
      v += __shfl_xor(v, 4); v += __shfl_xor(v, 8);
      if (ml == 0) xpart[wcol * 128 + mbase + (i >> 2) * 16 + q * 4 + (i & 3)] = v;
    }
  }
  __syncthreads();   // t1 reads done; eij partials visible

  // write mij into Tbuf; finalize eij
#pragma unroll
  for (int mt = 0; mt < 4; ++mt)
#pragma unroll
    for (int nt = 0; nt < 4; ++nt)
#pragma unroll
      for (int r = 0; r < 4; ++r) {
        int row = mbase + mt * 16 + q * 4 + r;
        int col = nbase + nt * 16 + ml;
        Tbuf[row * 132 + col] = __float2bfloat16(acc[mt][nt][r]);
      }
  if (tid < 128) eijL[tid] = sigm(xpart[tid] + xpart[128 + tid] + eibL[0]);
  __syncthreads();

  if (MODE == 0) {
    const float ev = eijL[se];
    float* mp = mi_f32 + (size_t)sdst * HID + sh * 64;
    const bf16* mr = Tbuf + se * 132 + sh * 64;
#pragma unroll
    for (int j = 0; j < 64; ++j)
      unsafeAtomicAdd(mp + j, __bfloat162float(mr[j]) * ev);
  }

  // ---------------- x branch: gate = tanh(silu(mij@xm_w1+b) . xm_w2) -------
#pragma unroll
  for (int a = 0; a < 4; ++a)
#pragma unroll
    for (int b = 0; b < 4; ++b) acc[a][b] = zf;
  for (int kc = 0; kc < 4; ++kc) {
    s16x8 af[4];
#pragma unroll
    for (int mt = 0; mt < 4; ++mt)
      af[mt] = ld_frag_lds(Tbuf + (mbase + mt * 16 + ml) * 132 + kc * 32 + q * 8);
#pragma unroll
    for (int nt = 0; nt < 4; ++nt) {
      const int n = nbase + nt * 16 + ml;
      s16x8 bfr = ld_frag_g(xw1p + (size_t)(kc * HID + n) * 32 + q * 8);
#pragma unroll
      for (int mt = 0; mt < 4; ++mt)
        acc[mt][nt] = __builtin_amdgcn_mfma_f32_16x16x32_bf16(af[mt], bfr, acc[mt][nt], 0, 0, 0);
    }
  }
  {
    float part[16];
#pragma unroll
    for (int i = 0; i < 16; ++i) part[i] = 0.f;
#pragma unroll
    for (int mt = 0; mt < 4; ++mt)
#pragma unroll
      for (int nt = 0; nt < 4; ++nt)
#pragma unroll
        for (int r = 0; r < 4; ++r) {
          int col = nbase + nt * 16 + ml;
          float v = acc[mt][nt][r] + xb1L[col];
          v *= sigm(v);
          part[mt * 4 + r] += v * w2xL[col];
        }
#pragma unroll
    for (int i = 0; i < 16; ++i) {
      float v = part[i];
      v += __shfl_xor(v, 1); v += __shfl_xor(v, 2);
      v += __shfl_xor(v, 4); v += __shfl_xor(v, 8);
      if (ml == 0) xpart[wcol * 128 + mbase + (i >> 2) * 16 + q * 4 + (i & 3)] = v;
    }
  }
  __syncthreads();

  if (MODE == 0) {
    if (tid < 128) {
      float g  = tanhf(xpart[tid] + xpart[128 + tid]);
      float sc = invdL[tid] * g;
      int dn = dsti[e0 + tid];
      unsafeAtomicAdd(xout + dn * 3 + 0, rxL[tid] * sc);
      unsafeAtomicAdd(xout + dn * 3 + 1, ryL[tid] * sc);
      unsafeAtomicAdd(xout + dn * 3 + 2, rzL[tid] * sc);
    }
    return;
  }

  // ---------------- MODE 1: in-block segmented reduction --------------------
  // fold gate into rx/ry/rz (reads xpart; xpart dies after this)
  if (tid < 128) {
    float g  = tanhf(xpart[tid] + xpart[128 + tid]);
    float sc = invdL[tid] * g;
    rxL[tid] *= sc; ryL[tid] *= sc; rzL[tid] *= sc;
  }
  __syncthreads();

  // build segment list via ballot (rows where dst changes)
  const bool flag = (tid < 128) && (tid == 0 || dstL[tid] != dstL[tid - 1]);
  const unsigned long long mask = __ballot(flag);
  const unsigned long long ltm = (1ULL << lane) - 1;
  if (wv == 0) {
    if (lane == 0) nsegA_p[0] = (int)__popcll(mask);
    if (flag) segstart[__popcll(mask & ltm)] = tid;
  }
  __syncthreads();
  if (wv == 1) {
    const int base = nsegA_p[0];
    if (flag) segstart[base + __popcll(mask & ltm)] = tid;
    if (lane == 0) {
      int ns = base + (int)__popcll(mask);
      nseg_p[0] = ns;
      segstart[ns] = 128;
    }
  }
  __syncthreads();
  const int nseg = nseg_p[0];
  if (tid < nseg) {
    const int r0 = segstart[tid], r1 = segstart[tid + 1];
    const int d  = dstL[r0];
    const int p0 = ptr[d], p1 = ptr[d + 1];
    const bool lX = p0 < e0 + r0;            // continues from previous block
    const bool rX = p1 > e0 + r1;            // continues into next block
    segmode[tid] = (!lX && !rX) ? 0 : (rX ? 2 : 1);   // 0=interior 1=head 2=tail
  }
  __syncthreads();

  // mi: sum rows of mij*eij per (segment, col)
  for (int t = tid; t < (nseg << 7); t += 256) {
    const int s = t >> 7, col = t & 127;
    const int r0 = segstart[s], r1 = segstart[s + 1];
    float a = 0.f;
    for (int r = r0; r < r1; ++r)
      a += __bfloat162float(Tbuf[r * 132 + col]) * eijL[r];
    const int mode = segmode[s];
    if (mode == 0)      mi_b[(size_t)dstL[r0] * HID + col] = __float2bfloat16(a);
    else if (mode == 2) tailrec[(size_t)blockIdx.x * HID + col] = a;
    else                headrec[(size_t)blockIdx.x * HID + col] = a;
  }
  // x: sum gated deltas per (segment, dim)
  for (int t = tid; t < nseg * 3; t += 256) {
    const int s = t / 3, d = t - s * 3;
    const int r0 = segstart[s], r1 = segstart[s + 1];
    const float* src = (d == 0) ? rxL : ((d == 1) ? ryL : rzL);
    float a = 0.f;
    for (int r = r0; r < r1; ++r) a += src[r];
    const int mode = segmode[s];
    const int dn = dstL[r0];
    if (mode == 0)      xout[dn * 3 + d] = x[dn * 3 + d] + a;
    else if (mode == 2) tailx[blockIdx.x * 3 + d] = a;
    else                headx[blockIdx.x * 3 + d] = a;
  }
}

// ---- fixup: spanning segments (sum partial records) + degree-0 nodes -------
__global__ __launch_bounds__(256, 8)
void fix_kernel(const int* __restrict__ ptr,
                const float* __restrict__ headrec, const float* __restrict__ tailrec,
                const float* __restrict__ headx, const float* __restrict__ tailx,
                const float* __restrict__ x, bf16* __restrict__ mi_b,
                float* __restrict__ xout) {
  const int wv = threadIdx.x >> 6, lane = threadIdx.x & 63;
  const int n = blockIdx.x * 4 + wv;
  if (n >= N_NODES) return;
  const int p0 = ptr[n], p1 = ptr[n + 1];
  if (p0 == p1) {           // degree 0
    *(unsigned*)(mi_b + (size_t)n * HID + lane * 2) = 0u;
    if (lane < 3) xout[n * 3 + lane] = x[n * 3 + lane];
    return;
  }
  const int B0 = p0 >> 7, B1 = (p1 - 1) >> 7;
  if (B0 == B1) return;     // interior, handled by edge kernel
  const int c0 = lane * 2;
  float a0 = 0.f, a1 = 0.f, xa = 0.f;
  for (int b = B0; b < B1; ++b) {
    a0 += tailrec[(size_t)b * HID + c0];
    a1 += tailrec[(size_t)b * HID + c0 + 1];
    if (lane < 3) xa += tailx[b * 3 + lane];
  }
  a0 += headrec[(size_t)B1 * HID + c0];
  a1 += headrec[(size_t)B1 * HID + c0 + 1];
  if (lane < 3) xa += headx[B1 * 3 + lane];
  union { bf16 h[2]; unsigned u; } o;
  o.h[0] = __float2bfloat16(a0);
  o.h[1] = __float2bfloat16(a1);
  *(unsigned*)(mi_b + (size_t)n * HID + c0) = o.u;
  if (lane < 3) xout[n * 3 + lane] = x[n * 3 + lane] + xa;
}

// ---- node kernel: h_out = h + MLP([mi|h]) ---------------------------------
__global__ __launch_bounds__(256, 2)
void node_kernel(const bf16* __restrict__ mi, const bf16* __restrict__ hb,
                 const float* __restrict__ h,
                 const bf16* __restrict__ nw1p, const bf16* __restrict__ nw2p,
                 const float* __restrict__ nb1, const float* __restrict__ nb2,
                 float* __restrict__ hout) {
  __shared__ bf16 Abuf[128 * 36];
  __shared__ bf16 Tbuf[128 * 132];
  __shared__ float b1L[HID], b2L[HID];
  const int tid = threadIdx.x;
  const int n0 = blockIdx.x * 128;
  if (tid < HID) { b1L[tid] = nb1[tid]; b2L[tid] = nb2[tid]; }
  const int lane = tid & 63, wv = tid >> 6;
  const int wrow = wv >> 1, wcol = wv & 1;
  const int q = lane >> 4, ml = lane & 15;
  const int mbase = wrow * 64, nbase = wcol * 64;
  const int se = tid >> 1, sh = tid & 1;
  int node = n0 + se;
  if (node >= N_NODES) node = 0;   // clamp; stores masked below

  const f32x4 zf = {0.f, 0.f, 0.f, 0.f};
  f32x4 acc[4][4];
#pragma unroll
  for (int a = 0; a < 4; ++a)
#pragma unroll
    for (int b = 0; b < 4; ++b) acc[a][b] = zf;

  for (int c = 0; c < 8; ++c) {    // K = 256: [mi | h], both bf16
    const bf16* p = ((c < 4) ? (mi + (size_t)node * HID + c * 32)
                             : (hb + (size_t)node * HID + (c - 4) * 32)) + sh * 16;
    uint4 v0 = *(const uint4*)p;
    uint4 v1 = *(const uint4*)(p + 8);
    bf16* d = Abuf + se * 36 + sh * 16;
    ((uint2*)d)[0] = make_uint2(v0.x, v0.y);
    ((uint2*)d)[1] = make_uint2(v0.z, v0.w);
    ((uint2*)d)[2] = make_uint2(v1.x, v1.y);
    ((uint2*)d)[3] = make_uint2(v1.z, v1.w);
    __syncthreads();
    s16x8 af[4];
#pragma unroll
    for (int mt = 0; mt < 4; ++mt)
      af[mt] = ld_frag_lds(Abuf + (mbase + mt * 16 + ml) * 36 + q * 8);
#pragma unroll
    for (int nt = 0; nt < 4; ++nt) {
      const int n = nbase + nt * 16 + ml;
      s16x8 bfr = ld_frag_g(nw1p + (size_t)(c * HID + n) * 32 + q * 8);
#pragma unroll
      for (int mt = 0; mt < 4; ++mt)
        acc[mt][nt] = __builtin_amdgcn_mfma_f32_16x16x32_bf16(af[mt], bfr, acc[mt][nt], 0, 0, 0);
    }
    __syncthreads();
  }
#pragma unroll
  for (int mt = 0; mt < 4; ++mt)
#pragma unroll
    for (int nt = 0; nt < 4; ++nt)
#pragma unroll
      for (int r = 0; r < 4; ++r) {
        int row = mbase + mt * 16 + q * 4 + r;
        int col = nbase + nt * 16 + ml;
        float v = acc[mt][nt][r] + b1L[col];
        v *= sigm(v);
        Tbuf[row * 132 + col] = __float2bfloat16(v);
      }
  __syncthreads();
#pragma unroll
  for (int a = 0; a < 4; ++a)
#pragma unroll
    for (int b = 0; b < 4; ++b) acc[a][b] = zf;
  for (int kc = 0; kc < 4; ++kc) {
    s16x8 af[4];
#pragma unroll
    for (int mt = 0; mt < 4; ++mt)
      af[mt] = ld_frag_lds(Tbuf + (mbase + mt * 16 + ml) * 132 + kc * 32 + q * 8);
#pragma unroll
    for (int nt = 0; nt < 4; ++nt) {
      const int n = nbase + nt * 16 + ml;
      s16x8 bfr = ld_frag_g(nw2p + (size_t)(kc * HID + n) * 32 + q * 8);
#pragma unroll
      for (int mt = 0; mt < 4; ++mt)
        acc[mt][nt] = __builtin_amdgcn_mfma_f32_16x16x32_bf16(af[mt], bfr, acc[mt][nt], 0, 0, 0);
    }
  }
#pragma unroll
  for (int mt = 0; mt < 4; ++mt)
#pragma unroll
    for (int nt = 0; nt < 4; ++nt)
#pragma unroll
      for (int r = 0; r < 4; ++r) {
        int row = mbase + mt * 16 + q * 4 + r;
        int nn = n0 + row;
        if (nn < N_NODES) {
          int col = nbase + nt * 16 + ml;
          size_t idx = (size_t)nn * HID + col;
          hout[idx] = h[idx] + acc[mt][nt][r] + b2L[col];
        }
      }
}

// ---- launcher --------------------------------------------------------------
extern "C" void kernel_launch(void* const* d_in, const int* in_sizes, int n_in,
                              void* d_out, int out_size, void* d_ws, size_t ws_size,
                              hipStream_t stream) {
  (void)in_sizes; (void)n_in; (void)out_size;
  const float* h     = (const float*)d_in[0];
  const float* x     = (const float*)d_in[1];
  const int*   eidx  = (const int*)  d_in[2];
  const float* eattr = (const float*)d_in[3];
  const float* em_w1 = (const float*)d_in[4];
  const float* em_b1 = (const float*)d_in[5];
  const float* em_w2 = (const float*)d_in[6];
  const float* em_b2 = (const float*)d_in[7];
  const float* ei_w  = (const float*)d_in[8];
  const float* ei_b  = (const float*)d_in[9];
  const float* xm_w1 = (const float*)d_in[10];
  const float* xm_b1 = (const float*)d_in[11];
  const float* xm_w2 = (const float*)d_in[12];
  const float* nm_w1 = (const float*)d_in[13];
  const float* nm_b1 = (const float*)d_in[14];
  const float* nm_w2 = (const float*)d_in[15];
  const float* nm_b2 = (const float*)d_in[16];

  float* hout = (float*)d_out;
  float* xout = hout + (size_t)N_NODES * HID;

  const int NB = (N_NODES + 255) / 256;        // 196
  const int NBLK = N_EDGES / 128;              // 5000

  char* w = (char*)d_ws;
  bf16* hb   = (bf16*)w;  w += (size_t)N_NODES * HID * 2;     // 12.8 MB
  bf16* mi_b = (bf16*)w;  w += (size_t)N_NODES * HID * 2;     // 12.8 MB
  bf16* w1p  = (bf16*)w;  w += 9 * HID * 32 * 2;
  bf16* w2p  = (bf16*)w;  w += 4 * HID * 32 * 2;
  bf16* xw1p = (bf16*)w;  w += 4 * HID * 32 * 2;
  bf16* nw1p = (bf16*)w;  w += 8 * HID * 32 * 2;
  bf16* nw2p = (bf16*)w;  w += 4 * HID * 32 * 2;
  int* cnt   = (int*)w;   w += (size_t)N_NODES * 4;
  int* work  = (int*)w;   w += (size_t)N_NODES * 4;
  int* ptr   = (int*)w;   w += (size_t)(N_NODES + 4) * 4;
  int* perm  = (int*)w;   w += (size_t)N_EDGES * 4;
  int* bsum  = (int*)w;   w += 256 * 4;
  int* boff  = (int*)w;   w += 256 * 4;
  float* headrec = (float*)w;  w += (size_t)NBLK * HID * 4;   // 2.56 MB
  float* tailrec = (float*)w;  w += (size_t)NBLK * HID * 4;   // 2.56 MB
  float* headx   = (float*)w;  w += (size_t)NBLK * 3 * 4;
  float* tailx   = (float*)w;  w += (size_t)NBLK * 3 * 4;
  float* mi_f32  = (float*)w;  // fallback only
  size_t need_sorted = (size_t)(w - (char*)d_ws);
  const bool sorted = (ws_size >= need_sorted);

  cvt_kernel<<<(N_NODES * HID + 255) / 256, 256, 0, stream>>>(h, hb, N_NODES * HID);
  pack_all_kernel<<<464, 256, 0, stream>>>(em_w1, em_w2, xm_w1, nm_w1, nm_w2,
                                           w1p, w2p, xw1p, nw1p, nw2p);

  if (sorted) {
    hipMemsetAsync(cnt, 0, (size_t)N_NODES * 4, stream);
    hist_kernel<<<(N_EDGES + 255) / 256, 256, 0, stream>>>(eidx + N_EDGES, cnt);
    scanA_kernel<<<NB, 256, 0, stream>>>(cnt, ptr, bsum);
    scanB_kernel<<<1, 256, 0, stream>>>(bsum, boff, NB);
    scanC_kernel<<<NB, 256, 0, stream>>>(ptr, work, boff, NB);
    scatter_kernel<<<(N_EDGES + 255) / 256, 256, 0, stream>>>(eidx + N_EDGES, work, perm);
    edge_kernel<1><<<NBLK, 256, 0, stream>>>(
        hb, x, eidx, eidx + N_EDGES, perm, ptr, eattr, w1p, w2p, xw1p,
        em_b1, em_b2, ei_w, ei_b, xm_b1, xm_w2,
        nullptr, xout, mi_b, headrec, tailrec, headx, tailx);
    fix_kernel<<<(N_NODES + 3) / 4, 256, 0, stream>>>(
        ptr, headrec, tailrec, headx, tailx, x, mi_b, xout);
  } else {
    hipMemsetAsync(mi_f32, 0, (size_t)N_NODES * HID * 4, stream);
    copy_x_kernel<<<(N_NODES * 3 + 255) / 256, 256, 0, stream>>>(x, xout, N_NODES * 3);
    edge_kernel<0><<<NBLK, 256, 0, stream>>>(
        hb, x, eidx, eidx + N_EDGES, nullptr, nullptr, eattr, w1p, w2p, xw1p,
        em_b1, em_b2, ei_w, ei_b, xm_b1, xm_w2,
        mi_f32, xout, nullptr, nullptr, nullptr, nullptr, nullptr);
    cvt_kernel<<<(N_NODES * HID + 255) / 256, 256, 0, stream>>>(mi_f32, mi_b, N_NODES * HID);
  }
  node_kernel<<<(N_NODES + 127) / 128, 256, 0, stream>>>(
      mi_b, hb, h, nw1p, nw2p, nm_b1, nm_b2, hout);
}

// Round 5
// 440.088 us; speedup vs baseline: 10.2112x; 1.2781x over previous
//
#include <hip/hip_runtime.h>
#include <hip/hip_bf16.h>

#define N_NODES 50000
#define N_EDGES 640000
#define HID 128

typedef float f32x4 __attribute__((ext_vector_type(4)));
typedef short s16x8 __attribute__((ext_vector_type(8)));
typedef __hip_bfloat16 bf16;

// ---- helpers ---------------------------------------------------------------
__device__ __forceinline__ s16x8 ld_frag_lds(const bf16* p) {
  union { uint2 u[2]; s16x8 v; } r;
  r.u[0] = *(const uint2*)(p);
  r.u[1] = *(const uint2*)(p + 4);
  return r.v;
}
__device__ __forceinline__ s16x8 ld_frag_g(const bf16* p) {
  union { uint4 u; s16x8 v; } r;
  r.u = *(const uint4*)(p);
  return r.v;
}
__device__ __forceinline__ f32x4 ld_f4(const float* p) { return *(const f32x4*)p; }
__device__ __forceinline__ float sigm(float v) { return 1.f / (1.f + __expf(-v)); }
__device__ __forceinline__ float b2f(unsigned short u) {
  return __uint_as_float(((unsigned)u) << 16);
}

// ---- prep kernels ----------------------------------------------------------
__global__ void cvt_kernel(const float* __restrict__ src, bf16* __restrict__ dst, int n) {
  int i = blockIdx.x * 256 + threadIdx.x;
  if (i < n) dst[i] = __float2bfloat16(src[i]);
}
__global__ void copy_x_kernel(const float* __restrict__ src, float* __restrict__ dst, int n) {
  int i = blockIdx.x * 256 + threadIdx.x;
  if (i < n) dst[i] = src[i];
}
// fp32 [K x 128] -> bf16 frag pack [kc][x][kk]: dst[kc*4096+x*32+kk]=src[(kc*32+kk)*128+x]
// (same layout serves A-operand (x=m) or B-operand (x=n) roles)
__device__ __forceinline__ void pack_one(const float* __restrict__ src,
                                         bf16* __restrict__ dst, int K, int i) {
  int kk = i & 31;
  int n  = (i >> 5) & 127;
  int kc = i >> 12;
  int k  = kc * 32 + kk;
  float v = (k < K) ? src[(size_t)k * HID + n] : 0.f;
  dst[i] = __float2bfloat16(v);
}
// merged: h->bf16 cvt (blocks < 6250, 4 elems/thread) + all weight packs
__global__ void cvtpack_kernel(const float* __restrict__ h,
                               const float* __restrict__ em_w1, const float* __restrict__ em_w2,
                               const float* __restrict__ xm_w1, const float* __restrict__ nm_w1,
                               const float* __restrict__ nm_w2,
                               bf16* __restrict__ hb,
                               bf16* __restrict__ w1p, bf16* __restrict__ w2p,
                               bf16* __restrict__ xw1p, bf16* __restrict__ nw1p,
                               bf16* __restrict__ nw2p) {
  const int bid = blockIdx.x;
  if (bid < 6250) {
    int i = (bid * 256 + threadIdx.x) * 4;
    f32x4 v = *(const f32x4*)(h + i);
    union { bf16 x[4]; uint2 u; } o;
#pragma unroll
    for (int r = 0; r < 4; ++r) o.x[r] = __float2bfloat16(v[r]);
    *(uint2*)(hb + i) = o.u;
    return;
  }
  int gid = (bid - 6250) * 256 + threadIdx.x;
  if      (gid < 36864)  pack_one(em_w1, w1p,  273, gid);
  else if (gid < 53248)  pack_one(em_w2, w2p,  128, gid - 36864);
  else if (gid < 69632)  pack_one(xm_w1, xw1p, 128, gid - 53248);
  else if (gid < 102400) pack_one(nm_w1, nw1p, 256, gid - 69632);
  else if (gid < 118784) pack_one(nm_w2, nw2p, 128, gid - 102400);
}

// ---- counting sort (CSR build) ---------------------------------------------
__global__ void hist_kernel(const int* __restrict__ dst, int* __restrict__ cnt) {
  int e = blockIdx.x * 256 + threadIdx.x;
  if (e < N_EDGES) atomicAdd(&cnt[dst[e]], 1);
}
__global__ void scanA_kernel(const int* __restrict__ cnt, int* __restrict__ ptr,
                             int* __restrict__ bsum) {
  __shared__ int s[256];
  const int tid = threadIdx.x;
  const int i = blockIdx.x * 256 + tid;
  int v = (i < N_NODES) ? cnt[i] : 0;
  s[tid] = v;
  __syncthreads();
  for (int off = 1; off < 256; off <<= 1) {
    int t = (tid >= off) ? s[tid - off] : 0;
    __syncthreads();
    s[tid] += t;
    __syncthreads();
  }
  if (i < N_NODES) ptr[i] = s[tid] - v;
  if (tid == 255) bsum[blockIdx.x] = s[255];
}
__global__ void scanB_kernel(const int* __restrict__ bsum, int* __restrict__ boff, int nb) {
  __shared__ int s[256];
  const int tid = threadIdx.x;
  int v = (tid < nb) ? bsum[tid] : 0;
  s[tid] = v;
  __syncthreads();
  for (int off = 1; off < 256; off <<= 1) {
    int t = (tid >= off) ? s[tid - off] : 0;
    __syncthreads();
    s[tid] += t;
    __syncthreads();
  }
  if (tid < nb) boff[tid] = s[tid] - v;
  if (tid == nb - 1) boff[nb] = s[tid];
}
__global__ void scanC_kernel(int* __restrict__ ptr, int* __restrict__ work,
                             const int* __restrict__ boff, int nb) {
  const int i = blockIdx.x * 256 + threadIdx.x;
  if (i < N_NODES) {
    int p = ptr[i] + boff[blockIdx.x];
    ptr[i] = p;
    work[i] = p;
  }
  if (blockIdx.x == 0 && threadIdx.x == 0) ptr[N_NODES] = boff[nb];
}
__global__ void scatter_kernel(const int* __restrict__ dst, int* __restrict__ work,
                               int* __restrict__ perm) {
  int e = blockIdx.x * 256 + threadIdx.x;
  if (e < N_EDGES) { int p = atomicAdd(&work[dst[e]], 1); perm[p] = e; }
}

// ---- fused edge kernel (TRANSPOSED GEMMs) ----------------------------------
// 256 threads, 2x2 wave grid. M-dim = output features (weights as A operand),
// N-dim = edges (staged rows as B operand). C'-layout: lane&15 = edge,
// (lane>>4)*4+r = out-feature -> vector b64 epilogue writes + float4 biases.
template<int MODE>
__global__ __launch_bounds__(256, 4)
void edge_kernel(const bf16* __restrict__ hb, const float* __restrict__ x,
                 const int* __restrict__ srci, const int* __restrict__ dsti,
                 const int* __restrict__ perm, const int* __restrict__ ptr,
                 const float* __restrict__ eattr,
                 const bf16* __restrict__ w1p, const bf16* __restrict__ w2p,
                 const bf16* __restrict__ xw1p,
                 const float* __restrict__ em_b1, const float* __restrict__ em_b2,
                 const float* __restrict__ ei_w, const float* __restrict__ ei_b,
                 const float* __restrict__ xm_b1, const float* __restrict__ xm_w2,
                 float* __restrict__ mi_f32, float* __restrict__ xout,
                 bf16* __restrict__ mi_b,
                 float* __restrict__ headrec, float* __restrict__ tailrec,
                 float* __restrict__ headx, float* __restrict__ tailx) {
  // LDS arena (39948 B -> 4 blocks/CU)
  __shared__ float arena[9987];
  bf16*  const smem  = (bf16*)arena;          // Abuf(2x4608) / Tbuf(128x132)
  float* const rxL   = arena + 8448;
  float* const ryL   = arena + 8576;
  float* const rzL   = arena + 8704;
  float* const invdL = arena + 8832;
  float* const eijL  = arena + 8960;
  float* const epart = arena + 9088;          // [2][128]
  float* const xpart = arena + 9344;          // [2][128]
  int*   const dstL     = (int*)(arena + 9600);   // [128]
  int*   const segstart = (int*)(arena + 9728);   // [129]
  int*   const segmode  = (int*)(arena + 9857);   // [128]
  int*   const nsegA_p  = (int*)(arena + 9985);
  int*   const nseg_p   = (int*)(arena + 9986);
  bf16*  const Abuf = smem;
  bf16*  const Tbuf = smem;

  const int tid = threadIdx.x;
  const int e0  = blockIdx.x * 128;
  const int lane = tid & 63, wv = tid >> 6;
  const int wrow = wv >> 1, wcol = wv & 1;
  const int q = lane >> 4, ml = lane & 15;
  const int mbase = wrow * 64, nbase = wcol * 64;

  const int se = tid >> 1, sh = tid & 1;      // 2 staging threads per edge row
  const int pos = e0 + se;
  const int eg  = (MODE == 1) ? perm[pos] : pos;
  const int sdst = dsti[eg], ssrc = srci[eg];
  if (sh == 0) dstL[se] = sdst;

  // chunk-8 payload: [d_sq | edge_attr(16) | zeros(15)]
  union U16 { bf16 h[16]; uint4 u[2]; } p8;
  {
    const float* ap = eattr + (size_t)eg * 16;
    if (sh == 0) {
      const float* xd = x + 3 * sdst;
      const float* xs = x + 3 * ssrc;
      float dx = xd[0] - xs[0], dy = xd[1] - xs[1], dz = xd[2] - xs[2];
      float dsq = dx * dx + dy * dy + dz * dz;
      rxL[se] = dx; ryL[se] = dy; rzL[se] = dz;
      invdL[se] = 1.f / (sqrtf(dsq + 1e-8f) + 1.f);
      p8.h[0] = __float2bfloat16(dsq);
#pragma unroll
      for (int j = 0; j < 15; ++j) p8.h[1 + j] = __float2bfloat16(ap[j]);
    } else {
      p8.h[0] = __float2bfloat16(ap[15]);
#pragma unroll
      for (int j = 1; j < 16; ++j) p8.h[j] = __float2bfloat16(0.f);
    }
  }

  const f32x4 zf = {0.f, 0.f, 0.f, 0.f};
  f32x4 acc[4][4];
#pragma unroll
  for (int a = 0; a < 4; ++a)
#pragma unroll
    for (int b = 0; b < 4; ++b) acc[a][b] = zf;

  // ---------------- stage 1: t1' = em_w1^T (x) edge_in^T, K = 288 ----------
  {
    const bf16* p = hb + (size_t)sdst * HID + sh * 16;
    uint4 a = *(const uint4*)p, b = *(const uint4*)(p + 8);
    bf16* d = Abuf + se * 36 + sh * 16;
    ((uint2*)d)[0] = make_uint2(a.x, a.y);
    ((uint2*)d)[1] = make_uint2(a.z, a.w);
    ((uint2*)d)[2] = make_uint2(b.x, b.y);
    ((uint2*)d)[3] = make_uint2(b.z, b.w);
  }
  __syncthreads();
  for (int c = 0; c < 9; ++c) {
    const int nxt = c + 1;
    uint4 n0v, n1v;
    if (nxt < 8) {
      const int node = (nxt < 4) ? sdst : ssrc;
      const bf16* p = hb + (size_t)node * HID + (nxt & 3) * 32 + sh * 16;
      n0v = *(const uint4*)p;
      n1v = *(const uint4*)(p + 8);
    } else if (nxt == 8) {
      n0v = p8.u[0]; n1v = p8.u[1];
    }
    const bf16* Ab = Abuf + (c & 1) * 4608;
    s16x8 be[4];
#pragma unroll
    for (int nt = 0; nt < 4; ++nt)
      be[nt] = ld_frag_lds(Ab + (nbase + nt * 16 + ml) * 36 + q * 8);
#pragma unroll
    for (int mt = 0; mt < 4; ++mt) {
      s16x8 aw = ld_frag_g(w1p + (size_t)(c * HID + mbase + mt * 16 + ml) * 32 + q * 8);
#pragma unroll
      for (int nt = 0; nt < 4; ++nt)
        acc[mt][nt] = __builtin_amdgcn_mfma_f32_16x16x32_bf16(aw, be[nt], acc[mt][nt], 0, 0, 0);
    }
    if (nxt <= 8) {
      bf16* d = Abuf + (nxt & 1) * 4608 + se * 36 + sh * 16;
      ((uint2*)d)[0] = make_uint2(n0v.x, n0v.y);
      ((uint2*)d)[1] = make_uint2(n0v.z, n0v.w);
      ((uint2*)d)[2] = make_uint2(n1v.x, n1v.y);
      ((uint2*)d)[3] = make_uint2(n1v.z, n1v.w);
    }
    __syncthreads();
  }

  // epilogue 1: silu -> Tbuf[edge][t1col], vector b64 writes
#pragma unroll
  for (int mt = 0; mt < 4; ++mt) {
    const int m0 = mbase + mt * 16 + q * 4;
    const f32x4 b1v = ld_f4(em_b1 + m0);
#pragma unroll
    for (int nt = 0; nt < 4; ++nt) {
      const int e = nbase + nt * 16 + ml;
      union { bf16 hh[4]; uint2 u; } o;
#pragma unroll
      for (int r = 0; r < 4; ++r) {
        float v = acc[mt][nt][r] + b1v[r];
        v *= sigm(v);
        o.hh[r] = __float2bfloat16(v);
      }
      *(uint2*)(Tbuf + e * 132 + m0) = o.u;
    }
  }
  __syncthreads();

  // ---------------- stage 2: mij' = em_w2^T (x) t1^T, K = 128 --------------
#pragma unroll
  for (int a = 0; a < 4; ++a)
#pragma unroll
    for (int b = 0; b < 4; ++b) acc[a][b] = zf;
  for (int kc = 0; kc < 4; ++kc) {
    s16x8 bt[4];
#pragma unroll
    for (int nt = 0; nt < 4; ++nt)
      bt[nt] = ld_frag_lds(Tbuf + (nbase + nt * 16 + ml) * 132 + kc * 32 + q * 8);
#pragma unroll
    for (int mt = 0; mt < 4; ++mt) {
      s16x8 aw = ld_frag_g(w2p + (size_t)(kc * HID + mbase + mt * 16 + ml) * 32 + q * 8);
#pragma unroll
      for (int nt = 0; nt < 4; ++nt)
        acc[mt][nt] = __builtin_amdgcn_mfma_f32_16x16x32_bf16(aw, bt[nt], acc[mt][nt], 0, 0, 0);
    }
  }
  // +b2 (regs); eij partials: 2 shuffles, lanes q==0 write epart
  {
    float pe[4] = {0.f, 0.f, 0.f, 0.f};
#pragma unroll
    for (int mt = 0; mt < 4; ++mt) {
      const int m0 = mbase + mt * 16 + q * 4;
      const f32x4 b2v = ld_f4(em_b2 + m0);
      const f32x4 ev  = ld_f4(ei_w + m0);
#pragma unroll
      for (int nt = 0; nt < 4; ++nt)
#pragma unroll
        for (int r = 0; r < 4; ++r) {
          float v = acc[mt][nt][r] + b2v[r];
          acc[mt][nt][r] = v;
          pe[nt] += v * ev[r];
        }
    }
#pragma unroll
    for (int nt = 0; nt < 4; ++nt) {
      pe[nt] += __shfl_xor(pe[nt], 16);
      pe[nt] += __shfl_xor(pe[nt], 32);
    }
    if (lane < 16) {
#pragma unroll
      for (int nt = 0; nt < 4; ++nt)
        epart[wrow * 128 + nbase + nt * 16 + ml] = pe[nt];
    }
  }
  __syncthreads();   // A: t1 frag reads done; epart visible

  // epilogue 2: Tbuf <- bf16(mij) (unscaled; reduce multiplies eij)
#pragma unroll
  for (int mt = 0; mt < 4; ++mt) {
    const int m0 = mbase + mt * 16 + q * 4;
#pragma unroll
    for (int nt = 0; nt < 4; ++nt) {
      const int e = nbase + nt * 16 + ml;
      union { bf16 hh[4]; uint2 u; } o;
#pragma unroll
      for (int r = 0; r < 4; ++r) o.hh[r] = __float2bfloat16(acc[mt][nt][r]);
      *(uint2*)(Tbuf + e * 132 + m0) = o.u;
    }
  }
  if (tid < 128) eijL[tid] = sigm(epart[tid] + epart[128 + tid] + ei_b[0]);
  __syncthreads();   // B: mij + eijL final

  // ---------------- x branch: xh' = xm_w1^T (x) mij^T (acc reused) ---------
#pragma unroll
  for (int a = 0; a < 4; ++a)
#pragma unroll
    for (int b = 0; b < 4; ++b) acc[a][b] = zf;
  for (int kc = 0; kc < 4; ++kc) {
    s16x8 bt[4];
#pragma unroll
    for (int nt = 0; nt < 4; ++nt)
      bt[nt] = ld_frag_lds(Tbuf + (nbase + nt * 16 + ml) * 132 + kc * 32 + q * 8);
#pragma unroll
    for (int mt = 0; mt < 4; ++mt) {
      s16x8 aw = ld_frag_g(xw1p + (size_t)(kc * HID + mbase + mt * 16 + ml) * 32 + q * 8);
#pragma unroll
      for (int nt = 0; nt < 4; ++nt)
        acc[mt][nt] = __builtin_amdgcn_mfma_f32_16x16x32_bf16(aw, bt[nt], acc[mt][nt], 0, 0, 0);
    }
  }
  {
    float px[4] = {0.f, 0.f, 0.f, 0.f};
#pragma unroll
    for (int mt = 0; mt < 4; ++mt) {
      const int m0 = mbase + mt * 16 + q * 4;
      const f32x4 xbv = ld_f4(xm_b1 + m0);
      const f32x4 wv2 = ld_f4(xm_w2 + m0);
#pragma unroll
      for (int nt = 0; nt < 4; ++nt)
#pragma unroll
        for (int r = 0; r < 4; ++r) {
          float v = acc[mt][nt][r] + xbv[r];
          v *= sigm(v);
          px[nt] += v * wv2[r];
        }
    }
#pragma unroll
    for (int nt = 0; nt < 4; ++nt) {
      px[nt] += __shfl_xor(px[nt], 16);
      px[nt] += __shfl_xor(px[nt], 32);
    }
    if (lane < 16) {
#pragma unroll
      for (int nt = 0; nt < 4; ++nt)
        xpart[wrow * 128 + nbase + nt * 16 + ml] = px[nt];
    }
  }
  __syncthreads();   // C: xpart visible

  // gate fold into rx/ry/rz
  if (tid < 128) {
    float g  = tanhf(xpart[tid] + xpart[128 + tid]);
    float sc = invdL[tid] * g;
    rxL[tid] *= sc; ryL[tid] *= sc; rzL[tid] *= sc;
  }

  if (MODE == 0) {
    __syncthreads();
    const float ev = eijL[se];
    const unsigned short* tr = (const unsigned short*)Tbuf + se * 132 + sh * 64;
    float* mp = mi_f32 + (size_t)sdst * HID + sh * 64;
#pragma unroll
    for (int j = 0; j < 64; ++j)
      unsafeAtomicAdd(mp + j, b2f(tr[j]) * ev);
    if (tid < 128) {
      int dn = dstL[tid];
      unsafeAtomicAdd(xout + dn * 3 + 0, rxL[tid]);
      unsafeAtomicAdd(xout + dn * 3 + 1, ryL[tid]);
      unsafeAtomicAdd(xout + dn * 3 + 2, rzL[tid]);
    }
    return;
  }

  // ---------------- MODE 1: in-block segmented reduction --------------------
  const bool flag = (tid < 128) && (tid == 0 || dstL[tid] != dstL[tid - 1]);
  const unsigned long long mask = __ballot(flag);
  const unsigned long long ltm = (1ULL << lane) - 1;
  if (wv == 0) {
    if (lane == 0) nsegA_p[0] = (int)__popcll(mask);
    if (flag) segstart[__popcll(mask & ltm)] = tid;
  }
  __syncthreads();
  if (wv == 1) {
    const int base = nsegA_p[0];
    if (flag) segstart[base + __popcll(mask & ltm)] = tid;
    if (lane == 0) {
      int ns = base + (int)__popcll(mask);
      nseg_p[0] = ns;
      segstart[ns] = 128;
    }
  }
  __syncthreads();
  const int nseg = nseg_p[0];
  if (tid < nseg) {
    const int r0 = segstart[tid], r1 = segstart[tid + 1];
    const int d  = dstL[r0];
    const int p0 = ptr[d], p1 = ptr[d + 1];
    const bool lX = p0 < e0 + r0;
    const bool rX = p1 > e0 + r1;
    segmode[tid] = (!lX && !rX) ? 0 : (rX ? 2 : 1);   // 0=interior 1=head 2=tail
  }
  __syncthreads();

  // mi: per (segment, col-pair) sum of eij*mij — vectorized 2-col reads
  for (int t = tid; t < (nseg << 6); t += 256) {
    const int s = t >> 6, c2 = (t & 63) * 2;
    const int r0 = segstart[s], r1 = segstart[s + 1];
    float a0 = 0.f, a1 = 0.f;
    for (int r = r0; r < r1; ++r) {
      const unsigned v = *(const unsigned*)(Tbuf + r * 132 + c2);
      const float ev = eijL[r];
      a0 += __uint_as_float(v << 16) * ev;
      a1 += __uint_as_float(v & 0xffff0000u) * ev;
    }
    const int mode = segmode[s];
    if (mode == 0) {
      union { bf16 hh[2]; unsigned u; } o;
      o.hh[0] = __float2bfloat16(a0);
      o.hh[1] = __float2bfloat16(a1);
      *(unsigned*)(mi_b + (size_t)dstL[r0] * HID + c2) = o.u;
    } else if (mode == 2) {
      tailrec[(size_t)blockIdx.x * HID + c2]     = a0;
      tailrec[(size_t)blockIdx.x * HID + c2 + 1] = a1;
    } else {
      headrec[(size_t)blockIdx.x * HID + c2]     = a0;
      headrec[(size_t)blockIdx.x * HID + c2 + 1] = a1;
    }
  }
  // x: per (segment, dim) sum of gated deltas
  for (int t = tid; t < nseg * 3; t += 256) {
    const int s = t / 3, d = t - s * 3;
    const int r0 = segstart[s], r1 = segstart[s + 1];
    const float* src = (d == 0) ? rxL : ((d == 1) ? ryL : rzL);
    float a = 0.f;
    for (int r = r0; r < r1; ++r) a += src[r];
    const int mode = segmode[s];
    const int dn = dstL[r0];
    if (mode == 0)      xout[dn * 3 + d] = x[dn * 3 + d] + a;
    else if (mode == 2) tailx[blockIdx.x * 3 + d] = a;
    else                headx[blockIdx.x * 3 + d] = a;
  }
}

// ---- fixup: spanning segments + degree-0 nodes -----------------------------
__global__ __launch_bounds__(256, 8)
void fix_kernel(const int* __restrict__ ptr,
                const float* __restrict__ headrec, const float* __restrict__ tailrec,
                const float* __restrict__ headx, const float* __restrict__ tailx,
                const float* __restrict__ x, bf16* __restrict__ mi_b,
                float* __restrict__ xout) {
  const int wv = threadIdx.x >> 6, lane = threadIdx.x & 63;
  const int n = blockIdx.x * 4 + wv;
  if (n >= N_NODES) return;
  const int p0 = ptr[n], p1 = ptr[n + 1];
  if (p0 == p1) {
    *(unsigned*)(mi_b + (size_t)n * HID + lane * 2) = 0u;
    if (lane < 3) xout[n * 3 + lane] = x[n * 3 + lane];
    return;
  }
  const int B0 = p0 >> 7, B1 = (p1 - 1) >> 7;
  if (B0 == B1) return;
  const int c0 = lane * 2;
  float a0 = 0.f, a1 = 0.f, xa = 0.f;
  for (int b = B0; b < B1; ++b) {
    a0 += tailrec[(size_t)b * HID + c0];
    a1 += tailrec[(size_t)b * HID + c0 + 1];
    if (lane < 3) xa += tailx[b * 3 + lane];
  }
  a0 += headrec[(size_t)B1 * HID + c0];
  a1 += headrec[(size_t)B1 * HID + c0 + 1];
  if (lane < 3) xa += headx[B1 * 3 + lane];
  union { bf16 h[2]; unsigned u; } o;
  o.h[0] = __float2bfloat16(a0);
  o.h[1] = __float2bfloat16(a1);
  *(unsigned*)(mi_b + (size_t)n * HID + c0) = o.u;
  if (lane < 3) xout[n * 3 + lane] = x[n * 3 + lane] + xa;
}

// ---- node kernel (TRANSPOSED, 64 nodes/block): h_out = h + MLP([mi|h]) -----
__global__ __launch_bounds__(256, 5)
void node_kernel(const bf16* __restrict__ mi, const bf16* __restrict__ hb,
                 const float* __restrict__ h,
                 const bf16* __restrict__ nw1p, const bf16* __restrict__ nw2p,
                 const float* __restrict__ nb1, const float* __restrict__ nb2,
                 float* __restrict__ hout) {
  __shared__ bf16 Abuf[64 * 36];
  __shared__ bf16 Tbuf[64 * 132];
  const int tid = threadIdx.x;
  const int n0 = blockIdx.x * 64;
  const int lane = tid & 63, wv = tid >> 6;
  const int wrow = wv >> 1, wcol = wv & 1;
  const int q = lane >> 4, ml = lane & 15;
  const int mbase = wrow * 64, nbase = wcol * 32;
  const int se = tid >> 2, sh = tid & 3;        // 4 staging threads per node
  int node = n0 + se;
  if (node >= N_NODES) node = N_NODES - 1;

  const f32x4 zf = {0.f, 0.f, 0.f, 0.f};
  f32x4 acc[4][2];
#pragma unroll
  for (int a = 0; a < 4; ++a)
#pragma unroll
    for (int b = 0; b < 2; ++b) acc[a][b] = zf;

  for (int c = 0; c < 8; ++c) {    // K = 256: [mi | h]
    const bf16* p = ((c < 4) ? (mi + (size_t)node * HID + c * 32)
                             : (hb + (size_t)node * HID + (c - 4) * 32)) + sh * 8;
    uint4 v = *(const uint4*)p;
    bf16* d = Abuf + se * 36 + sh * 8;
    ((uint2*)d)[0] = make_uint2(v.x, v.y);
    ((uint2*)d)[1] = make_uint2(v.z, v.w);
    __syncthreads();
    s16x8 bn[2];
#pragma unroll
    for (int nt = 0; nt < 2; ++nt)
      bn[nt] = ld_frag_lds(Abuf + (nbase + nt * 16 + ml) * 36 + q * 8);
#pragma unroll
    for (int mt = 0; mt < 4; ++mt) {
      s16x8 aw = ld_frag_g(nw1p + (size_t)(c * HID + mbase + mt * 16 + ml) * 32 + q * 8);
#pragma unroll
      for (int nt = 0; nt < 2; ++nt)
        acc[mt][nt] = __builtin_amdgcn_mfma_f32_16x16x32_bf16(aw, bn[nt], acc[mt][nt], 0, 0, 0);
    }
    __syncthreads();
  }
  // u = silu(. + b1) -> Tbuf[node][t1col] (b64 writes)
#pragma unroll
  for (int mt = 0; mt < 4; ++mt) {
    const int m0 = mbase + mt * 16 + q * 4;
    const f32x4 b1v = ld_f4(nb1 + m0);
#pragma unroll
    for (int nt = 0; nt < 2; ++nt) {
      const int e = nbase + nt * 16 + ml;
      union { bf16 hh[4]; uint2 u; } o;
#pragma unroll
      for (int r = 0; r < 4; ++r) {
        float v = acc[mt][nt][r] + b1v[r];
        v *= sigm(v);
        o.hh[r] = __float2bfloat16(v);
      }
      *(uint2*)(Tbuf + e * 132 + m0) = o.u;
    }
  }
  __syncthreads();
#pragma unroll
  for (int a = 0; a < 4; ++a)
#pragma unroll
    for (int b = 0; b < 2; ++b) acc[a][b] = zf;
  for (int kc = 0; kc < 4; ++kc) {
    s16x8 bt[2];
#pragma unroll
    for (int nt = 0; nt < 2; ++nt)
      bt[nt] = ld_frag_lds(Tbuf + (nbase + nt * 16 + ml) * 132 + kc * 32 + q * 8);
#pragma unroll
    for (int mt = 0; mt < 4; ++mt) {
      s16x8 aw = ld_frag_g(nw2p + (size_t)(kc * HID + mbase + mt * 16 + ml) * 32 + q * 8);
#pragma unroll
      for (int nt = 0; nt < 2; ++nt)
        acc[mt][nt] = __builtin_amdgcn_mfma_f32_16x16x32_bf16(aw, bt[nt], acc[mt][nt], 0, 0, 0);
    }
  }
  // h_out = h + (. + b2): float4 residual load + store
#pragma unroll
  for (int mt = 0; mt < 4; ++mt) {
    const int m0 = mbase + mt * 16 + q * 4;
    const f32x4 b2v = ld_f4(nb2 + m0);
#pragma unroll
    for (int nt = 0; nt < 2; ++nt) {
      const int nn = n0 + nbase + nt * 16 + ml;
      if (nn < N_NODES) {
        const f32x4 hv = ld_f4(h + (size_t)nn * HID + m0);
        f32x4 o;
#pragma unroll
        for (int r = 0; r < 4; ++r) o[r] = hv[r] + acc[mt][nt][r] + b2v[r];
        *(f32x4*)(hout + (size_t)nn * HID + m0) = o;
      }
    }
  }
}

// ---- launcher --------------------------------------------------------------
extern "C" void kernel_launch(void* const* d_in, const int* in_sizes, int n_in,
                              void* d_out, int out_size, void* d_ws, size_t ws_size,
                              hipStream_t stream) {
  (void)in_sizes; (void)n_in; (void)out_size;
  const float* h     = (const float*)d_in[0];
  const float* x     = (const float*)d_in[1];
  const int*   eidx  = (const int*)  d_in[2];
  const float* eattr = (const float*)d_in[3];
  const float* em_w1 = (const float*)d_in[4];
  const float* em_b1 = (const float*)d_in[5];
  const float* em_w2 = (const float*)d_in[6];
  const float* em_b2 = (const float*)d_in[7];
  const float* ei_w  = (const float*)d_in[8];
  const float* ei_b  = (const float*)d_in[9];
  const float* xm_w1 = (const float*)d_in[10];
  const float* xm_b1 = (const float*)d_in[11];
  const float* xm_w2 = (const float*)d_in[12];
  const float* nm_w1 = (const float*)d_in[13];
  const float* nm_b1 = (const float*)d_in[14];
  const float* nm_w2 = (const float*)d_in[15];
  const float* nm_b2 = (const float*)d_in[16];

  float* hout = (float*)d_out;
  float* xout = hout + (size_t)N_NODES * HID;

  const int NB   = (N_NODES + 255) / 256;      // 196
  const int NBLK = N_EDGES / 128;              // 5000

  char* w = (char*)d_ws;
  bf16* hb   = (bf16*)w;  w += (size_t)N_NODES * HID * 2;
  bf16* mi_b = (bf16*)w;  w += (size_t)N_NODES * HID * 2;
  bf16* w1p  = (bf16*)w;  w += 9 * HID * 32 * 2;
  bf16* w2p  = (bf16*)w;  w += 4 * HID * 32 * 2;
  bf16* xw1p = (bf16*)w;  w += 4 * HID * 32 * 2;
  bf16* nw1p = (bf16*)w;  w += 8 * HID * 32 * 2;
  bf16* nw2p = (bf16*)w;  w += 4 * HID * 32 * 2;
  int* cnt   = (int*)w;   w += (size_t)N_NODES * 4;
  int* work  = (int*)w;   w += (size_t)N_NODES * 4;
  int* ptr   = (int*)w;   w += (size_t)(N_NODES + 4) * 4;
  int* perm  = (int*)w;   w += (size_t)N_EDGES * 4;
  int* bsum  = (int*)w;   w += 256 * 4;
  int* boff  = (int*)w;   w += 256 * 4;
  float* headrec = (float*)w;  w += (size_t)NBLK * HID * 4;
  float* tailrec = (float*)w;  w += (size_t)NBLK * HID * 4;
  float* headx   = (float*)w;  w += (size_t)NBLK * 3 * 4;
  float* tailx   = (float*)w;  w += (size_t)NBLK * 3 * 4;
  float* mi_f32  = (float*)w;  // fallback only
  size_t need_sorted = (size_t)(w - (char*)d_ws);
  const bool sorted = (ws_size >= need_sorted);

  cvtpack_kernel<<<6250 + 464, 256, 0, stream>>>(h, em_w1, em_w2, xm_w1, nm_w1, nm_w2,
                                                 hb, w1p, w2p, xw1p, nw1p, nw2p);

  if (sorted) {
    hipMemsetAsync(cnt, 0, (size_t)N_NODES * 4, stream);
    hist_kernel<<<(N_EDGES + 255) / 256, 256, 0, stream>>>(eidx + N_EDGES, cnt);
    scanA_kernel<<<NB, 256, 0, stream>>>(cnt, ptr, bsum);
    scanB_kernel<<<1, 256, 0, stream>>>(bsum, boff, NB);
    scanC_kernel<<<NB, 256, 0, stream>>>(ptr, work, boff, NB);
    scatter_kernel<<<(N_EDGES + 255) / 256, 256, 0, stream>>>(eidx + N_EDGES, work, perm);
    edge_kernel<1><<<NBLK, 256, 0, stream>>>(
        hb, x, eidx, eidx + N_EDGES, perm, ptr, eattr, w1p, w2p, xw1p,
        em_b1, em_b2, ei_w, ei_b, xm_b1, xm_w2,
        nullptr, xout, mi_b, headrec, tailrec, headx, tailx);
    fix_kernel<<<(N_NODES + 3) / 4, 256, 0, stream>>>(
        ptr, headrec, tailrec, headx, tailx, x, mi_b, xout);
  } else {
    hipMemsetAsync(mi_f32, 0, (size_t)N_NODES * HID * 4, stream);
    copy_x_kernel<<<(N_NODES * 3 + 255) / 256, 256, 0, stream>>>(x, xout, N_NODES * 3);
    edge_kernel<0><<<NBLK, 256, 0, stream>>>(
        hb, x, eidx, eidx + N_EDGES, nullptr, nullptr, eattr, w1p, w2p, xw1p,
        em_b1, em_b2, ei_w, ei_b, xm_b1, xm_w2,
        mi_f32, xout, nullptr, nullptr, nullptr, nullptr, nullptr);
    cvt_kernel<<<(N_NODES * HID + 255) / 256, 256, 0, stream>>>(mi_f32, mi_b, N_NODES * HID);
  }
  node_kernel<<<(N_NODES + 63) / 64, 256, 0, stream>>>(
      mi_b, hb, h, nw1p, nw2p, nm_b1, nm_b2, hout);
}

// Round 6
// 422.911 us; speedup vs baseline: 10.6260x; 1.0406x over previous
//
#include <hip/hip_runtime.h>
#include <hip/hip_bf16.h>

#define N_NODES 50000
#define N_EDGES 640000
#define HID 128

typedef float f32x4 __attribute__((ext_vector_type(4)));
typedef short s16x8 __attribute__((ext_vector_type(8)));
typedef __hip_bfloat16 bf16;

// ---- helpers ---------------------------------------------------------------
__device__ __forceinline__ s16x8 ld_frag_lds(const bf16* p) {
  union { uint2 u[2]; s16x8 v; } r;
  r.u[0] = *(const uint2*)(p);
  r.u[1] = *(const uint2*)(p + 4);
  return r.v;
}
__device__ __forceinline__ s16x8 ld_frag_g(const bf16* p) {
  union { uint4 u; s16x8 v; } r;
  r.u = *(const uint4*)(p);
  return r.v;
}
__device__ __forceinline__ f32x4 ld_f4(const float* p) { return *(const f32x4*)p; }
// fast sigmoid: raw v_rcp (1 ulp) instead of IEEE div — saves ~3 ops/use
__device__ __forceinline__ float sigm(float v) {
  return __builtin_amdgcn_rcpf(1.f + __expf(-v));
}
__device__ __forceinline__ float tanh_fast(float x) {
  return 1.f - 2.f * __builtin_amdgcn_rcpf(__expf(2.f * x) + 1.f);
}
__device__ __forceinline__ float b2f(unsigned short u) {
  return __uint_as_float(((unsigned)u) << 16);
}
// packed f32x2 -> bf16x2 (single v_cvt_pk_bf16_f32 on gfx950)
#if defined(__has_builtin)
#if __has_builtin(__builtin_amdgcn_cvt_pk_bf16_f32)
#define HAS_PK_BF16 1
#endif
#endif
__device__ __forceinline__ unsigned pk_bf16(float a, float b) {
#ifdef HAS_PK_BF16
  typedef __bf16 bf16x2_t __attribute__((ext_vector_type(2)));
  bf16x2_t r = __builtin_amdgcn_cvt_pk_bf16_f32(a, b);
  unsigned u;
  __builtin_memcpy(&u, &r, 4);
  return u;
#else
  union { bf16 h[2]; unsigned u; } o;
  o.h[0] = __float2bfloat16(a);
  o.h[1] = __float2bfloat16(b);
  return o.u;
#endif
}

// ---- prep kernels ----------------------------------------------------------
__global__ void cvt_kernel(const float* __restrict__ src, bf16* __restrict__ dst, int n) {
  int i = blockIdx.x * 256 + threadIdx.x;
  if (i < n) dst[i] = __float2bfloat16(src[i]);
}
__global__ void copy_x_kernel(const float* __restrict__ src, float* __restrict__ dst, int n) {
  int i = blockIdx.x * 256 + threadIdx.x;
  if (i < n) dst[i] = src[i];
}
// fp32 [K x 128] -> bf16 frag pack [kc][x][kk]
__device__ __forceinline__ void pack_one(const float* __restrict__ src,
                                         bf16* __restrict__ dst, int K, int i) {
  int kk = i & 31;
  int n  = (i >> 5) & 127;
  int kc = i >> 12;
  int k  = kc * 32 + kk;
  float v = (k < K) ? src[(size_t)k * HID + n] : 0.f;
  dst[i] = __float2bfloat16(v);
}
// merged: h->bf16 cvt | weight packs | dst histogram (3 block ranges)
__global__ void cvtpack_kernel(const float* __restrict__ h,
                               const float* __restrict__ em_w1, const float* __restrict__ em_w2,
                               const float* __restrict__ xm_w1, const float* __restrict__ nm_w1,
                               const float* __restrict__ nm_w2,
                               bf16* __restrict__ hb,
                               bf16* __restrict__ w1p, bf16* __restrict__ w2p,
                               bf16* __restrict__ xw1p, bf16* __restrict__ nw1p,
                               bf16* __restrict__ nw2p,
                               const int* __restrict__ edst, int* __restrict__ cnt) {
  const int bid = blockIdx.x;
  if (bid < 6250) {
    int i = (bid * 256 + threadIdx.x) * 4;
    f32x4 v = *(const f32x4*)(h + i);
    uint2 o;
    o.x = pk_bf16(v[0], v[1]);
    o.y = pk_bf16(v[2], v[3]);
    *(uint2*)(hb + i) = o;
    return;
  }
  if (bid < 6714) {
    int gid = (bid - 6250) * 256 + threadIdx.x;
    if      (gid < 36864)  pack_one(em_w1, w1p,  273, gid);
    else if (gid < 53248)  pack_one(em_w2, w2p,  128, gid - 36864);
    else if (gid < 69632)  pack_one(xm_w1, xw1p, 128, gid - 53248);
    else if (gid < 102400) pack_one(nm_w1, nw1p, 256, gid - 69632);
    else if (gid < 118784) pack_one(nm_w2, nw2p, 128, gid - 102400);
    return;
  }
  if (cnt != nullptr) {
    int e = (bid - 6714) * 256 + threadIdx.x;
    if (e < N_EDGES) atomicAdd(&cnt[edst[e]], 1);
  }
}

// ---- CSR build (scan + scatter) --------------------------------------------
__global__ void scanA_kernel(const int* __restrict__ cnt, int* __restrict__ ptr,
                             int* __restrict__ bsum) {
  __shared__ int s[256];
  const int tid = threadIdx.x;
  const int i = blockIdx.x * 256 + tid;
  int v = (i < N_NODES) ? cnt[i] : 0;
  s[tid] = v;
  __syncthreads();
  for (int off = 1; off < 256; off <<= 1) {
    int t = (tid >= off) ? s[tid - off] : 0;
    __syncthreads();
    s[tid] += t;
    __syncthreads();
  }
  if (i < N_NODES) ptr[i] = s[tid] - v;
  if (tid == 255) bsum[blockIdx.x] = s[255];
}
__global__ void scanB_kernel(const int* __restrict__ bsum, int* __restrict__ boff, int nb) {
  __shared__ int s[256];
  const int tid = threadIdx.x;
  int v = (tid < nb) ? bsum[tid] : 0;
  s[tid] = v;
  __syncthreads();
  for (int off = 1; off < 256; off <<= 1) {
    int t = (tid >= off) ? s[tid - off] : 0;
    __syncthreads();
    s[tid] += t;
    __syncthreads();
  }
  if (tid < nb) boff[tid] = s[tid] - v;
  if (tid == nb - 1) boff[nb] = s[tid];
}
__global__ void scanC_kernel(int* __restrict__ ptr, int* __restrict__ work,
                             const int* __restrict__ boff, int nb) {
  const int i = blockIdx.x * 256 + threadIdx.x;
  if (i < N_NODES) {
    int p = ptr[i] + boff[blockIdx.x];
    ptr[i] = p;
    work[i] = p;
  }
  if (blockIdx.x == 0 && threadIdx.x == 0) ptr[N_NODES] = boff[nb];
}
__global__ void scatter_kernel(const int* __restrict__ dst, int* __restrict__ work,
                               int* __restrict__ perm) {
  int e = blockIdx.x * 256 + threadIdx.x;
  if (e < N_EDGES) { int p = atomicAdd(&work[dst[e]], 1); perm[p] = e; }
}

// ---- fused edge kernel (transposed GEMMs) ----------------------------------
template<int MODE>
__global__ __launch_bounds__(256, 4)
void edge_kernel(const bf16* __restrict__ hb, const float* __restrict__ x,
                 const int* __restrict__ srci, const int* __restrict__ dsti,
                 const int* __restrict__ perm, const int* __restrict__ ptr,
                 const float* __restrict__ eattr,
                 const bf16* __restrict__ w1p, const bf16* __restrict__ w2p,
                 const bf16* __restrict__ xw1p,
                 const float* __restrict__ em_b1, const float* __restrict__ em_b2,
                 const float* __restrict__ ei_w, const float* __restrict__ ei_b,
                 const float* __restrict__ xm_b1, const float* __restrict__ xm_w2,
                 float* __restrict__ mi_f32, float* __restrict__ xout,
                 bf16* __restrict__ mi_b,
                 float* __restrict__ headrec, float* __restrict__ tailrec,
                 float* __restrict__ headx, float* __restrict__ tailx) {
  __shared__ float arena[9987];
  bf16*  const smem  = (bf16*)arena;          // Abuf(2x4608) / Tbuf(128x132)
  float* const rxL   = arena + 8448;
  float* const ryL   = arena + 8576;
  float* const rzL   = arena + 8704;
  float* const invdL = arena + 8832;
  float* const eijL  = arena + 8960;
  float* const epart = arena + 9088;          // [2][128]
  float* const xpart = arena + 9344;          // [2][128]
  int*   const dstL     = (int*)(arena + 9600);
  int*   const segstart = (int*)(arena + 9728);
  int*   const segmode  = (int*)(arena + 9857);
  int*   const nsegA_p  = (int*)(arena + 9985);
  int*   const nseg_p   = (int*)(arena + 9986);
  bf16*  const Abuf = smem;
  bf16*  const Tbuf = smem;

  const int tid = threadIdx.x;
  const int e0  = blockIdx.x * 128;
  const int lane = tid & 63, wv = tid >> 6;
  const int wrow = wv >> 1, wcol = wv & 1;
  const int q = lane >> 4, ml = lane & 15;
  const int mbase = wrow * 64, nbase = wcol * 64;

  const int se = tid >> 1, sh = tid & 1;
  const int pos = e0 + se;
  const int eg  = (MODE == 1) ? perm[pos] : pos;
  const int sdst = dsti[eg], ssrc = srci[eg];
  if (sh == 0) dstL[se] = sdst;

  union U16 { bf16 h[16]; uint4 u[2]; } p8;
  {
    const float* ap = eattr + (size_t)eg * 16;
    if (sh == 0) {
      const float* xd = x + 3 * sdst;
      const float* xs = x + 3 * ssrc;
      float dx = xd[0] - xs[0], dy = xd[1] - xs[1], dz = xd[2] - xs[2];
      float dsq = dx * dx + dy * dy + dz * dz;
      rxL[se] = dx; ryL[se] = dy; rzL[se] = dz;
      invdL[se] = 1.f / (sqrtf(dsq + 1e-8f) + 1.f);
      p8.h[0] = __float2bfloat16(dsq);
#pragma unroll
      for (int j = 0; j < 15; ++j) p8.h[1 + j] = __float2bfloat16(ap[j]);
    } else {
      p8.h[0] = __float2bfloat16(ap[15]);
#pragma unroll
      for (int j = 1; j < 16; ++j) p8.h[j] = __float2bfloat16(0.f);
    }
  }

  const f32x4 zf = {0.f, 0.f, 0.f, 0.f};
  f32x4 acc[4][4];
#pragma unroll
  for (int a = 0; a < 4; ++a)
#pragma unroll
    for (int b = 0; b < 4; ++b) acc[a][b] = zf;

  // ---------------- stage 1: t1' = em_w1^T (x) edge_in^T, K = 288 ----------
  {
    const bf16* p = hb + (size_t)sdst * HID + sh * 16;
    uint4 a = *(const uint4*)p, b = *(const uint4*)(p + 8);
    bf16* d = Abuf + se * 36 + sh * 16;
    ((uint2*)d)[0] = make_uint2(a.x, a.y);
    ((uint2*)d)[1] = make_uint2(a.z, a.w);
    ((uint2*)d)[2] = make_uint2(b.x, b.y);
    ((uint2*)d)[3] = make_uint2(b.z, b.w);
  }
  __syncthreads();
  for (int c = 0; c < 9; ++c) {
    const int nxt = c + 1;
    uint4 n0v, n1v;
    if (nxt < 8) {
      const int node = (nxt < 4) ? sdst : ssrc;
      const bf16* p = hb + (size_t)node * HID + (nxt & 3) * 32 + sh * 16;
      n0v = *(const uint4*)p;
      n1v = *(const uint4*)(p + 8);
    } else if (nxt == 8) {
      n0v = p8.u[0]; n1v = p8.u[1];
    }
    const bf16* Ab = Abuf + (c & 1) * 4608;
    s16x8 be[4];
#pragma unroll
    for (int nt = 0; nt < 4; ++nt)
      be[nt] = ld_frag_lds(Ab + (nbase + nt * 16 + ml) * 36 + q * 8);
#pragma unroll
    for (int mt = 0; mt < 4; ++mt) {
      s16x8 aw = ld_frag_g(w1p + (size_t)(c * HID + mbase + mt * 16 + ml) * 32 + q * 8);
#pragma unroll
      for (int nt = 0; nt < 4; ++nt)
        acc[mt][nt] = __builtin_amdgcn_mfma_f32_16x16x32_bf16(aw, be[nt], acc[mt][nt], 0, 0, 0);
    }
    if (nxt <= 8) {
      bf16* d = Abuf + (nxt & 1) * 4608 + se * 36 + sh * 16;
      ((uint2*)d)[0] = make_uint2(n0v.x, n0v.y);
      ((uint2*)d)[1] = make_uint2(n0v.z, n0v.w);
      ((uint2*)d)[2] = make_uint2(n1v.x, n1v.y);
      ((uint2*)d)[3] = make_uint2(n1v.z, n1v.w);
    }
    __syncthreads();
  }

  // epilogue 1: silu -> Tbuf (packed cvt, b64 writes)
#pragma unroll
  for (int mt = 0; mt < 4; ++mt) {
    const int m0 = mbase + mt * 16 + q * 4;
    const f32x4 b1v = ld_f4(em_b1 + m0);
#pragma unroll
    for (int nt = 0; nt < 4; ++nt) {
      const int e = nbase + nt * 16 + ml;
      float v0 = acc[mt][nt][0] + b1v[0]; v0 *= sigm(v0);
      float v1 = acc[mt][nt][1] + b1v[1]; v1 *= sigm(v1);
      float v2 = acc[mt][nt][2] + b1v[2]; v2 *= sigm(v2);
      float v3 = acc[mt][nt][3] + b1v[3]; v3 *= sigm(v3);
      uint2 o;
      o.x = pk_bf16(v0, v1);
      o.y = pk_bf16(v2, v3);
      *(uint2*)(Tbuf + e * 132 + m0) = o;
    }
  }
  __syncthreads();

  // ---------------- stage 2: mij' = em_w2^T (x) t1^T, K = 128 --------------
#pragma unroll
  for (int a = 0; a < 4; ++a)
#pragma unroll
    for (int b = 0; b < 4; ++b) acc[a][b] = zf;
  for (int kc = 0; kc < 4; ++kc) {
    s16x8 bt[4];
#pragma unroll
    for (int nt = 0; nt < 4; ++nt)
      bt[nt] = ld_frag_lds(Tbuf + (nbase + nt * 16 + ml) * 132 + kc * 32 + q * 8);
#pragma unroll
    for (int mt = 0; mt < 4; ++mt) {
      s16x8 aw = ld_frag_g(w2p + (size_t)(kc * HID + mbase + mt * 16 + ml) * 32 + q * 8);
#pragma unroll
      for (int nt = 0; nt < 4; ++nt)
        acc[mt][nt] = __builtin_amdgcn_mfma_f32_16x16x32_bf16(aw, bt[nt], acc[mt][nt], 0, 0, 0);
    }
  }
  // +b2 (regs); eij partials: 2 shuffles
  {
    float pe[4] = {0.f, 0.f, 0.f, 0.f};
#pragma unroll
    for (int mt = 0; mt < 4; ++mt) {
      const int m0 = mbase + mt * 16 + q * 4;
      const f32x4 b2v = ld_f4(em_b2 + m0);
      const f32x4 ev  = ld_f4(ei_w + m0);
#pragma unroll
      for (int nt = 0; nt < 4; ++nt)
#pragma unroll
        for (int r = 0; r < 4; ++r) {
          float v = acc[mt][nt][r] + b2v[r];
          acc[mt][nt][r] = v;
          pe[nt] += v * ev[r];
        }
    }
#pragma unroll
    for (int nt = 0; nt < 4; ++nt) {
      pe[nt] += __shfl_xor(pe[nt], 16);
      pe[nt] += __shfl_xor(pe[nt], 32);
    }
    if (lane < 16) {
#pragma unroll
      for (int nt = 0; nt < 4; ++nt)
        epart[wrow * 128 + nbase + nt * 16 + ml] = pe[nt];
    }
  }
  __syncthreads();

  // epilogue 2: Tbuf <- bf16(mij) (packed cvt)
#pragma unroll
  for (int mt = 0; mt < 4; ++mt) {
    const int m0 = mbase + mt * 16 + q * 4;
#pragma unroll
    for (int nt = 0; nt < 4; ++nt) {
      const int e = nbase + nt * 16 + ml;
      uint2 o;
      o.x = pk_bf16(acc[mt][nt][0], acc[mt][nt][1]);
      o.y = pk_bf16(acc[mt][nt][2], acc[mt][nt][3]);
      *(uint2*)(Tbuf + e * 132 + m0) = o;
    }
  }
  if (tid < 128) eijL[tid] = sigm(epart[tid] + epart[128 + tid] + ei_b[0]);
  __syncthreads();

  // ---------------- x branch: xh' = xm_w1^T (x) mij^T ----------------------
#pragma unroll
  for (int a = 0; a < 4; ++a)
#pragma unroll
    for (int b = 0; b < 4; ++b) acc[a][b] = zf;
  for (int kc = 0; kc < 4; ++kc) {
    s16x8 bt[4];
#pragma unroll
    for (int nt = 0; nt < 4; ++nt)
      bt[nt] = ld_frag_lds(Tbuf + (nbase + nt * 16 + ml) * 132 + kc * 32 + q * 8);
#pragma unroll
    for (int mt = 0; mt < 4; ++mt) {
      s16x8 aw = ld_frag_g(xw1p + (size_t)(kc * HID + mbase + mt * 16 + ml) * 32 + q * 8);
#pragma unroll
      for (int nt = 0; nt < 4; ++nt)
        acc[mt][nt] = __builtin_amdgcn_mfma_f32_16x16x32_bf16(aw, bt[nt], acc[mt][nt], 0, 0, 0);
    }
  }
  {
    float px[4] = {0.f, 0.f, 0.f, 0.f};
#pragma unroll
    for (int mt = 0; mt < 4; ++mt) {
      const int m0 = mbase + mt * 16 + q * 4;
      const f32x4 xbv = ld_f4(xm_b1 + m0);
      const f32x4 wv2 = ld_f4(xm_w2 + m0);
#pragma unroll
      for (int nt = 0; nt < 4; ++nt)
#pragma unroll
        for (int r = 0; r < 4; ++r) {
          float v = acc[mt][nt][r] + xbv[r];
          v *= sigm(v);
          px[nt] += v * wv2[r];
        }
    }
#pragma unroll
    for (int nt = 0; nt < 4; ++nt) {
      px[nt] += __shfl_xor(px[nt], 16);
      px[nt] += __shfl_xor(px[nt], 32);
    }
    if (lane < 16) {
#pragma unroll
      for (int nt = 0; nt < 4; ++nt)
        xpart[wrow * 128 + nbase + nt * 16 + ml] = px[nt];
    }
  }
  __syncthreads();

  if (tid < 128) {
    float g  = tanh_fast(xpart[tid] + xpart[128 + tid]);
    float sc = invdL[tid] * g;
    rxL[tid] *= sc; ryL[tid] *= sc; rzL[tid] *= sc;
  }

  if (MODE == 0) {
    __syncthreads();
    const float ev = eijL[se];
    const unsigned short* tr = (const unsigned short*)Tbuf + se * 132 + sh * 64;
    float* mp = mi_f32 + (size_t)sdst * HID + sh * 64;
#pragma unroll
    for (int j = 0; j < 64; ++j)
      unsafeAtomicAdd(mp + j, b2f(tr[j]) * ev);
    if (tid < 128) {
      int dn = dstL[tid];
      unsafeAtomicAdd(xout + dn * 3 + 0, rxL[tid]);
      unsafeAtomicAdd(xout + dn * 3 + 1, ryL[tid]);
      unsafeAtomicAdd(xout + dn * 3 + 2, rzL[tid]);
    }
    return;
  }

  // ---------------- MODE 1: in-block segmented reduction --------------------
  const bool flag = (tid < 128) && (tid == 0 || dstL[tid] != dstL[tid - 1]);
  const unsigned long long mask = __ballot(flag);
  const unsigned long long ltm = (1ULL << lane) - 1;
  if (wv == 0) {
    if (lane == 0) nsegA_p[0] = (int)__popcll(mask);
    if (flag) segstart[__popcll(mask & ltm)] = tid;
  }
  __syncthreads();
  if (wv == 1) {
    const int base = nsegA_p[0];
    if (flag) segstart[base + __popcll(mask & ltm)] = tid;
    if (lane == 0) {
      int ns = base + (int)__popcll(mask);
      nseg_p[0] = ns;
      segstart[ns] = 128;
    }
  }
  __syncthreads();
  const int nseg = nseg_p[0];
  if (tid < nseg) {
    const int r0 = segstart[tid], r1 = segstart[tid + 1];
    const int d  = dstL[r0];
    const int p0 = ptr[d], p1 = ptr[d + 1];
    const bool lX = p0 < e0 + r0;
    const bool rX = p1 > e0 + r1;
    segmode[tid] = (!lX && !rX) ? 0 : (rX ? 2 : 1);
  }
  __syncthreads();

  // mi: per (segment, 4-col group) sum of eij*mij — uint2 LDS reads
  for (int t = tid; t < (nseg << 5); t += 256) {
    const int s = t >> 5, c4 = (t & 31) * 4;
    const int r0 = segstart[s], r1 = segstart[s + 1];
    float a0 = 0.f, a1 = 0.f, a2 = 0.f, a3 = 0.f;
    for (int r = r0; r < r1; ++r) {
      const uint2 v = *(const uint2*)(Tbuf + r * 132 + c4);
      const float ev = eijL[r];
      a0 += __uint_as_float(v.x << 16) * ev;
      a1 += __uint_as_float(v.x & 0xffff0000u) * ev;
      a2 += __uint_as_float(v.y << 16) * ev;
      a3 += __uint_as_float(v.y & 0xffff0000u) * ev;
    }
    const int mode = segmode[s];
    if (mode == 0) {
      uint2 o;
      o.x = pk_bf16(a0, a1);
      o.y = pk_bf16(a2, a3);
      *(uint2*)(mi_b + (size_t)dstL[r0] * HID + c4) = o;
    } else if (mode == 2) {
      f32x4 o = {a0, a1, a2, a3};
      *(f32x4*)(tailrec + (size_t)blockIdx.x * HID + c4) = o;
    } else {
      f32x4 o = {a0, a1, a2, a3};
      *(f32x4*)(headrec + (size_t)blockIdx.x * HID + c4) = o;
    }
  }
  // x: per (segment, dim) sum of gated deltas
  for (int t = tid; t < nseg * 3; t += 256) {
    const int s = t / 3, d = t - s * 3;
    const int r0 = segstart[s], r1 = segstart[s + 1];
    const float* src = (d == 0) ? rxL : ((d == 1) ? ryL : rzL);
    float a = 0.f;
    for (int r = r0; r < r1; ++r) a += src[r];
    const int mode = segmode[s];
    const int dn = dstL[r0];
    if (mode == 0)      xout[dn * 3 + d] = x[dn * 3 + d] + a;
    else if (mode == 2) tailx[blockIdx.x * 3 + d] = a;
    else                headx[blockIdx.x * 3 + d] = a;
  }
}

// ---- fixup: spanning segments + degree-0 nodes -----------------------------
__global__ __launch_bounds__(256, 8)
void fix_kernel(const int* __restrict__ ptr,
                const float* __restrict__ headrec, const float* __restrict__ tailrec,
                const float* __restrict__ headx, const float* __restrict__ tailx,
                const float* __restrict__ x, bf16* __restrict__ mi_b,
                float* __restrict__ xout) {
  const int wv = threadIdx.x >> 6, lane = threadIdx.x & 63;
  const int n = blockIdx.x * 4 + wv;
  if (n >= N_NODES) return;
  const int p0 = ptr[n], p1 = ptr[n + 1];
  if (p0 == p1) {
    *(unsigned*)(mi_b + (size_t)n * HID + lane * 2) = 0u;
    if (lane < 3) xout[n * 3 + lane] = x[n * 3 + lane];
    return;
  }
  const int B0 = p0 >> 7, B1 = (p1 - 1) >> 7;
  if (B0 == B1) return;
  const int c0 = lane * 2;
  float a0 = 0.f, a1 = 0.f, xa = 0.f;
  for (int b = B0; b < B1; ++b) {
    a0 += tailrec[(size_t)b * HID + c0];
    a1 += tailrec[(size_t)b * HID + c0 + 1];
    if (lane < 3) xa += tailx[b * 3 + lane];
  }
  a0 += headrec[(size_t)B1 * HID + c0];
  a1 += headrec[(size_t)B1 * HID + c0 + 1];
  if (lane < 3) xa += headx[B1 * 3 + lane];
  *(unsigned*)(mi_b + (size_t)n * HID + c0) = pk_bf16(a0, a1);
  if (lane < 3) xout[n * 3 + lane] = x[n * 3 + lane] + xa;
}

// ---- node kernel (transposed, 64 nodes/block) ------------------------------
__global__ __launch_bounds__(256, 5)
void node_kernel(const bf16* __restrict__ mi, const bf16* __restrict__ hb,
                 const float* __restrict__ h,
                 const bf16* __restrict__ nw1p, const bf16* __restrict__ nw2p,
                 const float* __restrict__ nb1, const float* __restrict__ nb2,
                 float* __restrict__ hout) {
  __shared__ bf16 Abuf[64 * 36];
  __shared__ bf16 Tbuf[64 * 132];
  const int tid = threadIdx.x;
  const int n0 = blockIdx.x * 64;
  const int lane = tid & 63, wv = tid >> 6;
  const int wrow = wv >> 1, wcol = wv & 1;
  const int q = lane >> 4, ml = lane & 15;
  const int mbase = wrow * 64, nbase = wcol * 32;
  const int se = tid >> 2, sh = tid & 3;
  int node = n0 + se;
  if (node >= N_NODES) node = N_NODES - 1;

  const f32x4 zf = {0.f, 0.f, 0.f, 0.f};
  f32x4 acc[4][2];
#pragma unroll
  for (int a = 0; a < 4; ++a)
#pragma unroll
    for (int b = 0; b < 2; ++b) acc[a][b] = zf;

  for (int c = 0; c < 8; ++c) {
    const bf16* p = ((c < 4) ? (mi + (size_t)node * HID + c * 32)
                             : (hb + (size_t)node * HID + (c - 4) * 32)) + sh * 8;
    uint4 v = *(const uint4*)p;
    bf16* d = Abuf + se * 36 + sh * 8;
    ((uint2*)d)[0] = make_uint2(v.x, v.y);
    ((uint2*)d)[1] = make_uint2(v.z, v.w);
    __syncthreads();
    s16x8 bn[2];
#pragma unroll
    for (int nt = 0; nt < 2; ++nt)
      bn[nt] = ld_frag_lds(Abuf + (nbase + nt * 16 + ml) * 36 + q * 8);
#pragma unroll
    for (int mt = 0; mt < 4; ++mt) {
      s16x8 aw = ld_frag_g(nw1p + (size_t)(c * HID + mbase + mt * 16 + ml) * 32 + q * 8);
#pragma unroll
      for (int nt = 0; nt < 2; ++nt)
        acc[mt][nt] = __builtin_amdgcn_mfma_f32_16x16x32_bf16(aw, bn[nt], acc[mt][nt], 0, 0, 0);
    }
    __syncthreads();
  }
#pragma unroll
  for (int mt = 0; mt < 4; ++mt) {
    const int m0 = mbase + mt * 16 + q * 4;
    const f32x4 b1v = ld_f4(nb1 + m0);
#pragma unroll
    for (int nt = 0; nt < 2; ++nt) {
      const int e = nbase + nt * 16 + ml;
      float v0 = acc[mt][nt][0] + b1v[0]; v0 *= sigm(v0);
      float v1 = acc[mt][nt][1] + b1v[1]; v1 *= sigm(v1);
      float v2 = acc[mt][nt][2] + b1v[2]; v2 *= sigm(v2);
      float v3 = acc[mt][nt][3] + b1v[3]; v3 *= sigm(v3);
      uint2 o;
      o.x = pk_bf16(v0, v1);
      o.y = pk_bf16(v2, v3);
      *(uint2*)(Tbuf + e * 132 + m0) = o;
    }
  }
  __syncthreads();
#pragma unroll
  for (int a = 0; a < 4; ++a)
#pragma unroll
    for (int b = 0; b < 2; ++b) acc[a][b] = zf;
  for (int kc = 0; kc < 4; ++kc) {
    s16x8 bt[2];
#pragma unroll
    for (int nt = 0; nt < 2; ++nt)
      bt[nt] = ld_frag_lds(Tbuf + (nbase + nt * 16 + ml) * 132 + kc * 32 + q * 8);
#pragma unroll
    for (int mt = 0; mt < 4; ++mt) {
      s16x8 aw = ld_frag_g(nw2p + (size_t)(kc * HID + mbase + mt * 16 + ml) * 32 + q * 8);
#pragma unroll
      for (int nt = 0; nt < 2; ++nt)
        acc[mt][nt] = __builtin_amdgcn_mfma_f32_16x16x32_bf16(aw, bt[nt], acc[mt][nt], 0, 0, 0);
    }
  }
#pragma unroll
  for (int mt = 0; mt < 4; ++mt) {
    const int m0 = mbase + mt * 16 + q * 4;
    const f32x4 b2v = ld_f4(nb2 + m0);
#pragma unroll
    for (int nt = 0; nt < 2; ++nt) {
      const int nn = n0 + nbase + nt * 16 + ml;
      if (nn < N_NODES) {
        const f32x4 hv = ld_f4(h + (size_t)nn * HID + m0);
        f32x4 o;
#pragma unroll
        for (int r = 0; r < 4; ++r) o[r] = hv[r] + acc[mt][nt][r] + b2v[r];
        *(f32x4*)(hout + (size_t)nn * HID + m0) = o;
      }
    }
  }
}

// ---- launcher --------------------------------------------------------------
extern "C" void kernel_launch(void* const* d_in, const int* in_sizes, int n_in,
                              void* d_out, int out_size, void* d_ws, size_t ws_size,
                              hipStream_t stream) {
  (void)in_sizes; (void)n_in; (void)out_size;
  const float* h     = (const float*)d_in[0];
  const float* x     = (const float*)d_in[1];
  const int*   eidx  = (const int*)  d_in[2];
  const float* eattr = (const float*)d_in[3];
  const float* em_w1 = (const float*)d_in[4];
  const float* em_b1 = (const float*)d_in[5];
  const float* em_w2 = (const float*)d_in[6];
  const float* em_b2 = (const float*)d_in[7];
  const float* ei_w  = (const float*)d_in[8];
  const float* ei_b  = (const float*)d_in[9];
  const float* xm_w1 = (const float*)d_in[10];
  const float* xm_b1 = (const float*)d_in[11];
  const float* xm_w2 = (const float*)d_in[12];
  const float* nm_w1 = (const float*)d_in[13];
  const float* nm_b1 = (const float*)d_in[14];
  const float* nm_w2 = (const float*)d_in[15];
  const float* nm_b2 = (const float*)d_in[16];

  float* hout = (float*)d_out;
  float* xout = hout + (size_t)N_NODES * HID;

  const int NB   = (N_NODES + 255) / 256;      // 196
  const int NBLK = N_EDGES / 128;              // 5000

  char* w = (char*)d_ws;
  bf16* hb   = (bf16*)w;  w += (size_t)N_NODES * HID * 2;
  bf16* mi_b = (bf16*)w;  w += (size_t)N_NODES * HID * 2;
  bf16* w1p  = (bf16*)w;  w += 9 * HID * 32 * 2;
  bf16* w2p  = (bf16*)w;  w += 4 * HID * 32 * 2;
  bf16* xw1p = (bf16*)w;  w += 4 * HID * 32 * 2;
  bf16* nw1p = (bf16*)w;  w += 8 * HID * 32 * 2;
  bf16* nw2p = (bf16*)w;  w += 4 * HID * 32 * 2;
  int* cnt   = (int*)w;   w += (size_t)N_NODES * 4;
  int* work  = (int*)w;   w += (size_t)N_NODES * 4;
  int* ptr   = (int*)w;   w += (size_t)(N_NODES + 4) * 4;
  int* perm  = (int*)w;   w += (size_t)N_EDGES * 4;
  int* bsum  = (int*)w;   w += 256 * 4;
  int* boff  = (int*)w;   w += 256 * 4;
  float* headrec = (float*)w;  w += (size_t)NBLK * HID * 4;
  float* tailrec = (float*)w;  w += (size_t)NBLK * HID * 4;
  float* headx   = (float*)w;  w += (size_t)NBLK * 3 * 4;
  float* tailx   = (float*)w;  w += (size_t)NBLK * 3 * 4;
  float* mi_f32  = (float*)w;  // fallback only
  size_t need_sorted = (size_t)(w - (char*)d_ws);
  const bool sorted = (ws_size >= need_sorted);

  if (sorted) {
    hipMemsetAsync(cnt, 0, (size_t)N_NODES * 4, stream);
    cvtpack_kernel<<<6250 + 464 + 2500, 256, 0, stream>>>(
        h, em_w1, em_w2, xm_w1, nm_w1, nm_w2,
        hb, w1p, w2p, xw1p, nw1p, nw2p, eidx + N_EDGES, cnt);
    scanA_kernel<<<NB, 256, 0, stream>>>(cnt, ptr, bsum);
    scanB_kernel<<<1, 256, 0, stream>>>(bsum, boff, NB);
    scanC_kernel<<<NB, 256, 0, stream>>>(ptr, work, boff, NB);
    scatter_kernel<<<(N_EDGES + 255) / 256, 256, 0, stream>>>(eidx + N_EDGES, work, perm);
    edge_kernel<1><<<NBLK, 256, 0, stream>>>(
        hb, x, eidx, eidx + N_EDGES, perm, ptr, eattr, w1p, w2p, xw1p,
        em_b1, em_b2, ei_w, ei_b, xm_b1, xm_w2,
        nullptr, xout, mi_b, headrec, tailrec, headx, tailx);
    fix_kernel<<<(N_NODES + 3) / 4, 256, 0, stream>>>(
        ptr, headrec, tailrec, headx, tailx, x, mi_b, xout);
  } else {
    cvtpack_kernel<<<6250 + 464, 256, 0, stream>>>(
        h, em_w1, em_w2, xm_w1, nm_w1, nm_w2,
        hb, w1p, w2p, xw1p, nw1p, nw2p, nullptr, nullptr);
    hipMemsetAsync(mi_f32, 0, (size_t)N_NODES * HID * 4, stream);
    copy_x_kernel<<<(N_NODES * 3 + 255) / 256, 256, 0, stream>>>(x, xout, N_NODES * 3);
    edge_kernel<0><<<NBLK, 256, 0, stream>>>(
        hb, x, eidx, eidx + N_EDGES, nullptr, nullptr, eattr, w1p, w2p, xw1p,
        em_b1, em_b2, ei_w, ei_b, xm_b1, xm_w2,
        mi_f32, xout, nullptr, nullptr, nullptr, nullptr, nullptr);
    cvt_kernel<<<(N_NODES * HID + 255) / 256, 256, 0, stream>>>(mi_f32, mi_b, N_NODES * HID);
  }
  node_kernel<<<(N_NODES + 63) / 64, 256, 0, stream>>>(
      mi_b, hb, h, nw1p, nw2p, nm_b1, nm_b2, hout);
}